// Round 10
// baseline (557.570 us; speedup 1.0000x reference)
//
#include <hip/hip_runtime.h>
#include <hip/hip_bf16.h>

constexpr int TN = 100000;   // nodes
constexpr int TE = 200000;   // edges
constexpr int TG = 4000;     // graphs
constexpr int TH = 128;      // hidden

using short8 = __attribute__((ext_vector_type(8))) short;
using f32x4  = __attribute__((ext_vector_type(4))) float;
typedef __hip_bfloat16 bf16;

#define DEVINL __device__ __forceinline__
DEVINL float sigm(float x)  { return 1.f / (1.f + __expf(-x)); }
DEVINL float ftanh(float x) { return 1.f - 2.f / (__expf(2.f * x) + 1.f); }
DEVINL void unpack8(uint4 v, float* f) {
    const ushort* u = (const ushort*)&v;
#pragma unroll
    for (int j = 0; j < 8; ++j) f[j] = __bfloat162float(*(const bf16*)&u[j]);
}

// async global->LDS, 16B per lane; dest = uniform base + lane*16
DEVINL void gload_lds16(const ushort* gsrc, ushort* ldst) {
    __builtin_amdgcn_global_load_lds(
        (const __attribute__((address_space(1))) void*)gsrc,
        (__attribute__((address_space(3))) void*)ldst, 16, 0, 0);
}

// ================= merged weight conversion =================
__global__ void convAll(const float* __restrict__ g1, const float* __restrict__ g2,
                        const float* __restrict__ e1, const float* __restrict__ e2,
                        const float* __restrict__ gwih, const float* __restrict__ gwhh,
                        const float* __restrict__ lwih, const float* __restrict__ lwhh,
                        bf16* __restrict__ w6, bf16* __restrict__ wgru,
                        bf16* __restrict__ wl) {
    int i = blockIdx.x * 256 + threadIdx.x;
    if (i < 6 * TH * TH) {
        int m = i >> 14, r = i & 16383;
        int n = r >> 7, k = r & 127;
        const float* s = (m == 0) ? g1 : (m == 1) ? g1 + TH * TH
                       : (m == 2) ? g2 : (m == 3) ? g2 + TH * TH
                       : (m == 4) ? e1 : e2;
        w6[i] = __float2bfloat16(s[k * TH + n]);
        return;
    }
    i -= 6 * TH * TH;
    if (i < 2 * 384 * TH) {
        const float* s = (i < 384 * TH) ? gwih : gwhh;
        int r = (i < 384 * TH) ? i : i - 384 * TH;
        wgru[i] = __float2bfloat16(s[r]);
        return;
    }
    i -= 2 * 384 * TH;
    if (i < 512 * 256) {
        int c = i >> 8, k = i & 255;
        float v = (k < 128) ? lwih[c * 256 + k] + lwhh[c * 128 + k] : lwih[c * 256 + k];
        wl[i] = __float2bfloat16(v);
    }
}

// ================= node projection: 64 rows/block ============
template<int K>
__global__ __launch_bounds__(256) void proj64(const float* __restrict__ X,
                                              const float* __restrict__ W,
                                              const float* __restrict__ b,
                                              ushort* __restrict__ out, int M) {
    __shared__ float xs[64][K];
    int tid = threadIdx.x;
    int bm = blockIdx.x * 64;
    for (int i = tid; i < 64 * K; i += 256) {
        int r = i / K, k = i % K;
        xs[r][k] = (bm + r < M) ? X[(size_t)(bm + r) * K + k] : 0.f;
    }
    __syncthreads();
    int rb = tid >> 4, h0 = (tid & 15) * 8;
    float acc[4][8];
#pragma unroll
    for (int j = 0; j < 4; ++j)
#pragma unroll
        for (int c = 0; c < 8; ++c) acc[j][c] = b[h0 + c];
#pragma unroll
    for (int k = 0; k < K; ++k) {
        float4 w0 = *(const float4*)(W + k * TH + h0);
        float4 w1 = *(const float4*)(W + k * TH + h0 + 4);
#pragma unroll
        for (int j = 0; j < 4; ++j) {
            float xv = xs[rb + 16 * j][k];
            acc[j][0] = fmaf(xv, w0.x, acc[j][0]); acc[j][1] = fmaf(xv, w0.y, acc[j][1]);
            acc[j][2] = fmaf(xv, w0.z, acc[j][2]); acc[j][3] = fmaf(xv, w0.w, acc[j][3]);
            acc[j][4] = fmaf(xv, w1.x, acc[j][4]); acc[j][5] = fmaf(xv, w1.y, acc[j][5]);
            acc[j][6] = fmaf(xv, w1.z, acc[j][6]); acc[j][7] = fmaf(xv, w1.w, acc[j][7]);
        }
    }
#pragma unroll
    for (int j = 0; j < 4; ++j) {
        int row = bm + rb + 16 * j;
        if (row >= M) continue;
        ushort o[8];
#pragma unroll
        for (int c = 0; c < 8; ++c) {
            bf16 v = __float2bfloat16(acc[j][c]);
            o[c] = *(ushort*)&v;
        }
        *(uint4*)(out + (size_t)row * TH + h0) = *(uint4*)o;
    }
}

// ===== proj_scatter: K=4 projection with CSR-slot scatter (layer-0 e0) =====
__global__ __launch_bounds__(256) void proj_scatter(
    const float* __restrict__ X, const float* __restrict__ W,
    const float* __restrict__ b, const int* __restrict__ perm,
    ushort* __restrict__ out, int M) {
    __shared__ float xs[64][4];
    int tid = threadIdx.x;
    int bm = blockIdx.x * 64;
    if (tid < 64) {
        float4 a = make_float4(0.f, 0.f, 0.f, 0.f);
        if (bm + tid < M) a = *(const float4*)(X + (size_t)(bm + tid) * 4);
        xs[tid][0] = a.x; xs[tid][1] = a.y; xs[tid][2] = a.z; xs[tid][3] = a.w;
    }
    __syncthreads();
    int rb = tid >> 4, h0 = (tid & 15) * 8;
    float acc[4][8];
#pragma unroll
    for (int j = 0; j < 4; ++j)
#pragma unroll
        for (int c = 0; c < 8; ++c) acc[j][c] = b[h0 + c];
#pragma unroll
    for (int k = 0; k < 4; ++k) {
        float4 w0 = *(const float4*)(W + k * TH + h0);
        float4 w1 = *(const float4*)(W + k * TH + h0 + 4);
#pragma unroll
        for (int j = 0; j < 4; ++j) {
            float xv = xs[rb + 16 * j][k];
            acc[j][0] = fmaf(xv, w0.x, acc[j][0]); acc[j][1] = fmaf(xv, w0.y, acc[j][1]);
            acc[j][2] = fmaf(xv, w0.z, acc[j][2]); acc[j][3] = fmaf(xv, w0.w, acc[j][3]);
            acc[j][4] = fmaf(xv, w1.x, acc[j][4]); acc[j][5] = fmaf(xv, w1.y, acc[j][5]);
            acc[j][6] = fmaf(xv, w1.z, acc[j][6]); acc[j][7] = fmaf(xv, w1.w, acc[j][7]);
        }
    }
#pragma unroll
    for (int j = 0; j < 4; ++j) {
        int row = bm + rb + 16 * j;
        if (row >= M) continue;
        ushort o[8];
#pragma unroll
        for (int c = 0; c < 8; ++c) {
            bf16 v = __float2bfloat16(acc[j][c]);
            o[c] = *(ushort*)&v;
        }
        *(uint4*)(out + (size_t)perm[row] * TH + h0) = *(uint4*)o;
    }
}

// ================= CSR build =================
__global__ void count_deg(const int* __restrict__ ei_dst, int* __restrict__ deg, int En) {
    int e = blockIdx.x * 256 + threadIdx.x;
    if (e < En) atomicAdd(&deg[ei_dst[e]], 1);
}
__global__ void scan_block(const int* __restrict__ deg, int* __restrict__ rowptr,
                           int* __restrict__ bsum, int Nn) {
    __shared__ int sm[256];
    int tid = threadIdx.x;
    int gid = blockIdx.x * 256 + tid;
    int v = (gid < Nn) ? deg[gid] : 0;
    int x = v;
    sm[tid] = x; __syncthreads();
    for (int off = 1; off < 256; off <<= 1) {
        int t = (tid >= off) ? sm[tid - off] : 0;
        __syncthreads();
        x += t; sm[tid] = x;
        __syncthreads();
    }
    if (gid < Nn) rowptr[gid] = x - v;
    if (tid == 255) bsum[blockIdx.x] = x;
}
__global__ void scan_bsum(const int* __restrict__ bsum, int* __restrict__ bsumx, int nb) {
    __shared__ int sm[512];
    int tid = threadIdx.x;
    int v = (tid < nb) ? bsum[tid] : 0;
    int x = v;
    sm[tid] = x; __syncthreads();
    for (int off = 1; off < 512; off <<= 1) {
        int t = (tid >= off) ? sm[tid - off] : 0;
        __syncthreads();
        x += t; sm[tid] = x;
        __syncthreads();
    }
    if (tid < nb) bsumx[tid] = x - v;
}
__global__ void add_off(int* __restrict__ rowptr, const int* __restrict__ bsumx,
                        int Nn, int Etot) {
    int gid = blockIdx.x * 256 + threadIdx.x;
    if (gid < Nn) rowptr[gid] += bsumx[gid >> 8];
    if (gid == 0) rowptr[Nn] = Etot;
}
__global__ void fill_csr(const int* __restrict__ ei_src, const int* __restrict__ ei_dst,
                         const int* __restrict__ rowptr, int* __restrict__ cur,
                         int* __restrict__ srcp, int* __restrict__ epos, int En) {
    int e = blockIdx.x * 256 + threadIdx.x;
    if (e >= En) return;
    int d = ei_dst[e];
    int p = atomicAdd(&cur[d], 1);
    int slot = rowptr[d] + p;
    srcp[slot] = ei_src[e];
    epos[e] = slot;
}
__global__ void build_gptr(const int* __restrict__ batch, int* __restrict__ gptr,
                           int Nn, int Gn) {
    int n = blockIdx.x * 256 + threadIdx.x;
    if (n >= Nn) return;
    int bc = batch[n];
    int bp = (n == 0) ? -1 : batch[n - 1];
    for (int g = bp + 1; g <= bc; ++g) gptr[g] = n;
    if (n == Nn - 1) for (int g = bc + 1; g <= Gn; ++g) gptr[g] = Nn;
}

// ========== aggregation, 16 threads/node, 8 ch/thread, 2-way unroll ==========
__global__ __launch_bounds__(256) void aggregate_v8(
    const ushort* __restrict__ node, const ushort* __restrict__ ef,
    const int* __restrict__ srcp, const int* __restrict__ rowptr,
    const float* __restrict__ eps, int l, ushort* __restrict__ zb, int Nn) {
    int t = blockIdx.x * 256 + threadIdx.x;
    int n = t >> 4;
    if (n >= Nn) return;
    int c8 = (t & 15) * 8;
    float se = 1.f + eps[l];
    float acc[8];
    uint4 nv = *(const uint4*)(node + (size_t)n * TH + c8);
    unpack8(nv, acc);
#pragma unroll
    for (int j = 0; j < 8; ++j) acc[j] *= se;
    int s0 = rowptr[n], s1 = rowptr[n + 1];
    int i = s0;
    for (; i + 1 < s1; i += 2) {
        int sa = srcp[i], sb = srcp[i + 1];
        uint4 av0 = *(const uint4*)(node + (size_t)sa * TH + c8);
        uint4 bv0 = *(const uint4*)(ef + (size_t)i * TH + c8);
        uint4 av1 = *(const uint4*)(node + (size_t)sb * TH + c8);
        uint4 bv1 = *(const uint4*)(ef + (size_t)(i + 1) * TH + c8);
        float a0[8], b0[8], a1[8], b1[8];
        unpack8(av0, a0); unpack8(bv0, b0);
        unpack8(av1, a1); unpack8(bv1, b1);
#pragma unroll
        for (int j = 0; j < 8; ++j)
            acc[j] += fmaxf(a0[j] + b0[j], 0.f) + fmaxf(a1[j] + b1[j], 0.f);
    }
    if (i < s1) {
        int sa = srcp[i];
        uint4 av = *(const uint4*)(node + (size_t)sa * TH + c8);
        uint4 bv = *(const uint4*)(ef + (size_t)i * TH + c8);
        float af[8], bf[8];
        unpack8(av, af); unpack8(bv, bf);
#pragma unroll
        for (int j = 0; j < 8; ++j) acc[j] += fmaxf(af[j] + bf[j], 0.f);
    }
    ushort o[8];
#pragma unroll
    for (int j = 0; j < 8; ++j) {
        bf16 v = __float2bfloat16(acc[j]);
        o[j] = *(ushort*)&v;
    }
    *(uint4*)(zb + (size_t)n * TH + c8) = *(uint4*)o;
}

// ===== fused 2-layer MLP (R5/R7 form): one tile per block, single 32 KB LDS =====
__global__ __launch_bounds__(256, 2) void mlp2_fused(
    const ushort* __restrict__ A, const ushort* __restrict__ W1t,
    const float* __restrict__ b1, const ushort* __restrict__ W2t,
    const float* __restrict__ b2, ushort* __restrict__ C, int M)
{
    __shared__ ushort As[128 * 128];
    const int tid = threadIdx.x;
    const int bm = blockIdx.x * 128;
    const int lane = tid & 63, w = tid >> 6;
    const int lr = lane & 15, lq = lane >> 4;
    const int wm = (w & 1) * 64, wn = (w >> 1) * 64;
    short8 wf[4][4];
#pragma unroll
    for (int ni = 0; ni < 4; ++ni)
#pragma unroll
        for (int ks = 0; ks < 4; ++ks)
            wf[ni][ks] = *(const short8*)(W1t + (size_t)(wn + ni * 16 + lr) * 128 + ks * 32 + lq * 8);
    // async staging: wave w covers slots [w*512, w*512+512)
#pragma unroll
    for (int i = 0; i < 8; ++i) {
        int s = w * 512 + i * 64 + lane;
        int r = s >> 4;
        int c = (s & 15) ^ (r & 15);
        gload_lds16(A + (size_t)(bm + r) * 128 + c * 8, As + (w * 512 + i * 64) * 8);
    }
    __syncthreads();
    f32x4 acc[4][4] = {};
#pragma unroll
    for (int ks = 0; ks < 4; ++ks) {
        int cb = ks * 4 + lq;
        short8 af[4];
#pragma unroll
        for (int mi = 0; mi < 4; ++mi)
            af[mi] = *(const short8*)(&As[(wm + mi * 16 + lr) * 128 + ((cb ^ lr) * 8)]);
#pragma unroll
        for (int mi = 0; mi < 4; ++mi)
#pragma unroll
            for (int ni = 0; ni < 4; ++ni)
                acc[mi][ni] = __builtin_amdgcn_mfma_f32_16x16x32_bf16(af[mi], wf[ni][ks], acc[mi][ni], 0, 0, 0);
    }
    __syncthreads();   // all As reads complete before in-place T write
#pragma unroll
    for (int mi = 0; mi < 4; ++mi)
#pragma unroll
        for (int reg = 0; reg < 4; ++reg) {
            int row = wm + mi * 16 + lq * 4 + reg;
#pragma unroll
            for (int ni = 0; ni < 4; ++ni) {
                int col = wn + ni * 16 + lr;
                float v = fmaxf(acc[mi][ni][reg] + b1[col], 0.f);
                bf16 bv = __float2bfloat16(v);
                As[row * 128 + (((col >> 3) ^ (row & 15)) * 8) + (col & 7)] = *(ushort*)&bv;
            }
        }
    // preload W2 (independent of LDS; latency hides under barrier)
#pragma unroll
    for (int ni = 0; ni < 4; ++ni)
#pragma unroll
        for (int ks = 0; ks < 4; ++ks)
            wf[ni][ks] = *(const short8*)(W2t + (size_t)(wn + ni * 16 + lr) * 128 + ks * 32 + lq * 8);
    __syncthreads();
    {
        f32x4 acc2[4][4] = {};
#pragma unroll
        for (int ks = 0; ks < 4; ++ks) {
            int cb = ks * 4 + lq;
            short8 af[4];
#pragma unroll
            for (int mi = 0; mi < 4; ++mi)
                af[mi] = *(const short8*)(&As[(wm + mi * 16 + lr) * 128 + ((cb ^ lr) * 8)]);
#pragma unroll
            for (int mi = 0; mi < 4; ++mi)
#pragma unroll
                for (int ni = 0; ni < 4; ++ni)
                    acc2[mi][ni] = __builtin_amdgcn_mfma_f32_16x16x32_bf16(af[mi], wf[ni][ks], acc2[mi][ni], 0, 0, 0);
        }
#pragma unroll
        for (int mi = 0; mi < 4; ++mi)
#pragma unroll
            for (int reg = 0; reg < 4; ++reg) {
                int row = bm + wm + mi * 16 + lq * 4 + reg;
                if (row >= M) continue;
#pragma unroll
                for (int ni = 0; ni < 4; ++ni) {
                    int col = wn + ni * 16 + lr;
                    bf16 bv = __float2bfloat16(acc2[mi][ni][reg] + b2[col]);
                    C[(size_t)row * 128 + col] = *(ushort*)&bv;
                }
            }
    }
}

// ===== fused GRU v6 (R8 proven): weight-stationary, dbuf, counted vmcnt, grid 512 =====
__global__ __launch_bounds__(512, 2) void gru_fused(
    const ushort* __restrict__ mfeat, const ushort* __restrict__ wih,
    const ushort* __restrict__ whh, const float* __restrict__ bih,
    const float* __restrict__ bhh, ushort* __restrict__ node, int Nn, int nT)
{
    __shared__ ushort Ms[2][64 * 128];
    __shared__ ushort Hs[2][64 * 128];
    const int tid = threadIdx.x;
    const int lane = tid & 63, w = tid >> 6;
    const int lr = lane & 15, lq = lane >> 4;
    const int col = w * 16 + lr;
    short8 W[6][4];
#pragma unroll
    for (int ks = 0; ks < 4; ++ks) {
        int koff = ks * 32 + lq * 8;
        W[0][ks] = *(const short8*)(wih + (size_t)col * 128 + koff);
        W[1][ks] = *(const short8*)(wih + (size_t)(128 + col) * 128 + koff);
        W[2][ks] = *(const short8*)(wih + (size_t)(256 + col) * 128 + koff);
        W[3][ks] = *(const short8*)(whh + (size_t)col * 128 + koff);
        W[4][ks] = *(const short8*)(whh + (size_t)(128 + col) * 128 + koff);
        W[5][ks] = *(const short8*)(whh + (size_t)(256 + col) * 128 + koff);
    }
    const float br  = bih[col] + bhh[col];
    const float bz  = bih[128 + col] + bhh[128 + col];
    const float bin = bih[256 + col], bhn = bhh[256 + col];

    auto stage = [&](int tt, int buf) {
#pragma unroll
        for (int i = 0; i < 2; ++i) {
            int sb = w * 128 + i * 64;
            int s = sb + lane;
            int r = s >> 4;
            int c = (s & 15) ^ (r & 15);
            size_t goff = (size_t)(tt * 64 + r) * 128 + c * 8;
            gload_lds16(mfeat + goff, &Ms[buf][sb * 8]);
            gload_lds16(node + goff, &Hs[buf][sb * 8]);
        }
    };

    int t = blockIdx.x;
    const int G = gridDim.x;
    if (t >= nT) return;
    stage(t, 0);
    int cur = 0;
    while (t < nT) {
        int tn = t + G;
        if (tn < nT) {
            stage(tn, cur ^ 1);
            asm volatile("s_waitcnt vmcnt(4)" ::: "memory");
        } else {
            asm volatile("s_waitcnt vmcnt(0)" ::: "memory");
        }
        __builtin_amdgcn_sched_barrier(0);
        __builtin_amdgcn_s_barrier();
        __builtin_amdgcn_sched_barrier(0);
        {
            const ushort* Mc = Ms[cur];
            const ushort* Hc = Hs[cur];
            f32x4 aR[4] = {}, aZ[4] = {}, aN[4] = {}, aH[4] = {};
#pragma unroll
            for (int ks = 0; ks < 4; ++ks) {
                int cb = ks * 4 + lq;
#pragma unroll
                for (int rt = 0; rt < 4; ++rt) {
                    int off = (rt * 16 + lr) * 128 + ((cb ^ lr) * 8);
                    short8 am = *(const short8*)(&Mc[off]);
                    short8 ah = *(const short8*)(&Hc[off]);
                    aR[rt] = __builtin_amdgcn_mfma_f32_16x16x32_bf16(am, W[0][ks], aR[rt], 0, 0, 0);
                    aR[rt] = __builtin_amdgcn_mfma_f32_16x16x32_bf16(ah, W[3][ks], aR[rt], 0, 0, 0);
                    aZ[rt] = __builtin_amdgcn_mfma_f32_16x16x32_bf16(am, W[1][ks], aZ[rt], 0, 0, 0);
                    aZ[rt] = __builtin_amdgcn_mfma_f32_16x16x32_bf16(ah, W[4][ks], aZ[rt], 0, 0, 0);
                    aN[rt] = __builtin_amdgcn_mfma_f32_16x16x32_bf16(am, W[2][ks], aN[rt], 0, 0, 0);
                    aH[rt] = __builtin_amdgcn_mfma_f32_16x16x32_bf16(ah, W[5][ks], aH[rt], 0, 0, 0);
                }
            }
            const int bm = t * 64;
#pragma unroll
            for (int rt = 0; rt < 4; ++rt)
#pragma unroll
                for (int reg = 0; reg < 4; ++reg) {
                    int lrow = rt * 16 + lq * 4 + reg;
                    int row = bm + lrow;
                    if (row >= Nn) continue;
                    float r = sigm(aR[rt][reg] + br);
                    float z = sigm(aZ[rt][reg] + bz);
                    float n = ftanh(aN[rt][reg] + bin + r * (aH[rt][reg] + bhn));
                    int hofs = lrow * 128 + (((col >> 3) ^ (lrow & 15)) * 8) + (col & 7);
                    float hold = __bfloat162float(*(const bf16*)&Hc[hofs]);
                    bf16 hv = __float2bfloat16((1.f - z) * n + z * hold);
                    node[(size_t)row * 128 + col] = *(ushort*)&hv;
                }
        }
        __builtin_amdgcn_sched_barrier(0);
        __builtin_amdgcn_s_barrier();
        __builtin_amdgcn_sched_barrier(0);
        cur ^= 1;
        t = tn;
    }
}

// ===== fused Set2Set v2: de-conflicted LDS, per-lane-node score, reg cell state =====
// Pads: qf/rf [16][136], es [16][520] -> group gi bank offset = 8 (no cross-group
// conflicts); score pass: lane l16 owns nodes l16+16k, full 128-ch dot per lane
// (qf reads are group-broadcast = free); cell state in registers (same thread
// mapping every step).
__global__ __launch_bounds__(256) void set2set_fused(
    const ushort* __restrict__ node, const ushort* __restrict__ Wl,
    const float* __restrict__ bih, const float* __restrict__ bhh,
    const int* __restrict__ gptr,
    const float* __restrict__ w1, const float* __restrict__ b1,
    const float* __restrict__ w2, const float* __restrict__ b2,
    float* __restrict__ out, int Gn)
{
    __shared__ ushort qsb[16 * 256];   // [graph][256ch] bf16, lstm swizzle layout
    __shared__ float  qf[16][136];     // q (= hl), padded
    __shared__ float  rf[16][136];     // r, padded
    __shared__ float  es[16][520];     // attention scores, padded
    const int tid = threadIdx.x;
    const int bm = blockIdx.x * 16;
    for (int i = tid; i < 16 * 256; i += 256) qsb[i] = 0;
    __syncthreads();
    const int lane = tid & 63, w = tid >> 6;
    const int lr = lane & 15, lq = lane >> 4;
    const int gi = tid >> 4, l16 = tid & 15;   // att group: one 16-lane slice per graph
    const int g = bm + gi;
    const bool live = g < Gn;
    const int n0 = live ? gptr[g] : 0;
    const int n1 = live ? gptr[g + 1] : 0;
    int cnt = n1 - n0; if (cnt > 512) cnt = 512;
    float creg[2][4] = {{0.f, 0.f, 0.f, 0.f}, {0.f, 0.f, 0.f, 0.f}};  // lstm cell

    for (int step = 0; step < 3; ++step) {
        // ---- LSTM on 16 graphs (MFMA; layout identical to old lstm_fused) ----
        f32x4 acc[4][2] = {};
#pragma unroll
        for (int ks = 0; ks < 8; ++ks) {
            int cb = ks * 4 + lq;
            short8 am = *(const short8*)(&qsb[lr * 256 + ((cb ^ lr) * 8)]);
            int koff = ks * 32 + lq * 8;
#pragma unroll
            for (int gg = 0; gg < 4; ++gg)
#pragma unroll
                for (int sub = 0; sub < 2; ++sub) {
                    int col = gg * 128 + w * 32 + sub * 16 + lr;
                    short8 bf = *(const short8*)(Wl + (size_t)col * 256 + koff);
                    acc[gg][sub] = __builtin_amdgcn_mfma_f32_16x16x32_bf16(am, bf, acc[gg][sub], 0, 0, 0);
                }
        }
        __syncthreads();   // all qsb reads done before epilogue overwrites
#pragma unroll
        for (int sub = 0; sub < 2; ++sub) {
            int h = w * 32 + sub * 16 + lr;
            float bi = bih[h] + bhh[h];
            float bff = bih[128 + h] + bhh[128 + h];
            float bg = bih[256 + h] + bhh[256 + h];
            float bo = bih[384 + h] + bhh[384 + h];
#pragma unroll
            for (int reg = 0; reg < 4; ++reg) {
                int row = lq * 4 + reg;
                float iv = sigm(acc[0][sub][reg] + bi);
                float fv = sigm(acc[1][sub][reg] + bff);
                float gv = ftanh(acc[2][sub][reg] + bg);
                float ov = sigm(acc[3][sub][reg] + bo);
                float c = fv * creg[sub][reg] + iv * gv;
                creg[sub][reg] = c;
                float hv = ov * ftanh(c);
                qf[row][h] = hv;
                bf16 hb = __float2bfloat16(hv);
                qsb[row * 256 + (((h >> 3) ^ row) * 8) + (h & 7)] = *(ushort*)&hb;
            }
        }
        __syncthreads();   // qf ready for attention
        // ---- score: lane l16 owns nodes l16+16k; full 128-ch dot per lane ----
        for (int i = l16; i < cnt; i += 16) {
            const ushort* nr = node + (size_t)(n0 + i) * 128;
            float p = 0.f;
#pragma unroll
            for (int c = 0; c < 16; ++c) {
                uint4 v = *(const uint4*)(nr + c * 8);
                float f[8]; unpack8(v, f);
#pragma unroll
                for (int j = 0; j < 8; ++j) p = fmaf(f[j], qf[gi][c * 8 + j], p);
            }
            es[gi][i] = p;
        }
        // ---- softmax over this graph's nodes (16-lane group reduce) ----
        float m = -1e30f;
        for (int i = l16; i < cnt; i += 16) m = fmaxf(m, es[gi][i]);
#pragma unroll
        for (int off = 8; off; off >>= 1) m = fmaxf(m, __shfl_xor(m, off, 16));
        float sm = 0.f;
        for (int i = l16; i < cnt; i += 16) {
            float ex = __expf(es[gi][i] - m);
            es[gi][i] = ex;
            sm += ex;
        }
#pragma unroll
        for (int off = 8; off; off >>= 1) sm += __shfl_xor(sm, off, 16);
        float inv = 1.f / fmaxf(sm, 1e-9f);
        // ---- weighted sum: lane l16 owns channels l16*8..+7, loops all nodes ----
        float racc[8] = {};
        for (int i = 0; i < cnt; ++i) {
            uint4 v = *(const uint4*)(node + (size_t)(n0 + i) * 128 + l16 * 8);
            float f[8]; unpack8(v, f);
            float a = es[gi][i];
#pragma unroll
            for (int j = 0; j < 8; ++j) racc[j] = fmaf(a, f[j], racc[j]);
        }
#pragma unroll
        for (int j = 0; j < 8; ++j) {
            int h = l16 * 8 + j;
            float rv = racc[j] * inv;
            rf[gi][h] = rv;
            int h2 = 128 + h;
            bf16 rb = __float2bfloat16(rv);
            qsb[gi * 256 + (((h2 >> 3) ^ gi) * 8) + (h2 & 7)] = *(ushort*)&rb;
        }
        __syncthreads();   // qsb (q+r) ready for next step; rf for FC
    }
    // ---- final FC per graph: out = relu([q,r] @ w1 + b1) @ w2 + b2 ----
    if (live) {
        int h0 = l16 * 8;
        float acch[8];
#pragma unroll
        for (int j = 0; j < 8; ++j) acch[j] = b1[h0 + j];
        for (int k = 0; k < 128; ++k) {
            float qk = qf[gi][k];
            const float* wr = w1 + (size_t)k * 128 + h0;
            float4 w0 = *(const float4*)wr, w4 = *(const float4*)(wr + 4);
            acch[0] = fmaf(qk, w0.x, acch[0]); acch[1] = fmaf(qk, w0.y, acch[1]);
            acch[2] = fmaf(qk, w0.z, acch[2]); acch[3] = fmaf(qk, w0.w, acch[3]);
            acch[4] = fmaf(qk, w4.x, acch[4]); acch[5] = fmaf(qk, w4.y, acch[5]);
            acch[6] = fmaf(qk, w4.z, acch[6]); acch[7] = fmaf(qk, w4.w, acch[7]);
        }
        for (int k = 0; k < 128; ++k) {
            float qk = rf[gi][k];
            const float* wr = w1 + (size_t)(128 + k) * 128 + h0;
            float4 w0 = *(const float4*)wr, w4 = *(const float4*)(wr + 4);
            acch[0] = fmaf(qk, w0.x, acch[0]); acch[1] = fmaf(qk, w0.y, acch[1]);
            acch[2] = fmaf(qk, w0.z, acch[2]); acch[3] = fmaf(qk, w0.w, acch[3]);
            acch[4] = fmaf(qk, w4.x, acch[4]); acch[5] = fmaf(qk, w4.y, acch[5]);
            acch[6] = fmaf(qk, w4.z, acch[6]); acch[7] = fmaf(qk, w4.w, acch[7]);
        }
        float p = 0.f;
#pragma unroll
        for (int j = 0; j < 8; ++j) p += fmaxf(acch[j], 0.f) * w2[h0 + j];
#pragma unroll
        for (int off = 8; off; off >>= 1) p += __shfl_xor(p, off, 16);
        if (l16 == 0) out[g] = p + b2[0];
    }
}

// ---------------------------------------------------------------------------
static void launch_mlp2(const void* A, const bf16* W1t, const float* b1,
                        const bf16* W2t, const float* b2, void* C, int M, hipStream_t s) {
    hipLaunchKernelGGL(mlp2_fused, dim3((M + 127) / 128), dim3(256), 0, s,
                       (const ushort*)A, (const ushort*)W1t, b1, (const ushort*)W2t, b2,
                       (ushort*)C, M);
}

extern "C" void kernel_launch(void* const* d_in, const int* in_sizes, int n_in,
                              void* d_out, int out_size, void* d_ws, size_t ws_size,
                              hipStream_t stream) {
    const float* x         = (const float*)d_in[0];
    const float* edge_attr = (const float*)d_in[1];
    const int*   edge_index= (const int*)d_in[2];
    const int*   batch     = (const int*)d_in[3];
    const float* node_w    = (const float*)d_in[4];
    const float* node_b    = (const float*)d_in[5];
    const float* edge_w    = (const float*)d_in[6];
    const float* edge_b    = (const float*)d_in[7];
    const float* eps       = (const float*)d_in[8];
    const float* gin_w1    = (const float*)d_in[9];
    const float* gin_b1    = (const float*)d_in[10];
    const float* gin_w2    = (const float*)d_in[11];
    const float* gin_b2    = (const float*)d_in[12];
    const float* em_w1     = (const float*)d_in[13];
    const float* em_b1     = (const float*)d_in[14];
    const float* em_w2     = (const float*)d_in[15];
    const float* em_b2     = (const float*)d_in[16];
    const float* gru_wih   = (const float*)d_in[17];
    const float* gru_whh   = (const float*)d_in[18];
    const float* gru_bih   = (const float*)d_in[19];
    const float* gru_bhh   = (const float*)d_in[20];
    const float* lstm_wih  = (const float*)d_in[21];
    const float* lstm_whh  = (const float*)d_in[22];
    const float* lstm_bih  = (const float*)d_in[23];
    const float* lstm_bhh  = (const float*)d_in[24];
    const float* fc_w1     = (const float*)d_in[25];
    const float* fc_b1     = (const float*)d_in[26];
    const float* fc_w2     = (const float*)d_in[27];
    const float* fc_b2     = (const float*)d_in[28];
    float* out = (float*)d_out;
    const int* ei_src = edge_index;
    const int* ei_dst = edge_index + TE;

    // ---- workspace layout ----
    char* base = (char*)d_ws;
    size_t off = 0;
    auto alloc = [&](size_t bytes) { void* p = base + off; off += (bytes + 15) & ~size_t(15); return p; };
    bf16*  nodeb = (bf16*)alloc((size_t)TN * TH * 2);   // 25.6 MB
    bf16*  zb    = (bf16*)alloc((size_t)TN * TH * 2);   // 25.6 MB
    bf16*  e1b   = (bf16*)alloc((size_t)TE * TH * 2);   // 51.2 MB
    int*   deg   = (int*)alloc((size_t)TN * 4);
    int*   rowptr= (int*)alloc((size_t)(TN + 1) * 4);
    int*   cur   = (int*)alloc((size_t)TN * 4);
    int*   srcp  = (int*)alloc((size_t)TE * 4);
    int*   epos  = (int*)alloc((size_t)TE * 4);
    int*   bsum  = (int*)alloc(512 * 4);
    int*   bsumx = (int*)alloc(512 * 4);
    int*   gptr  = (int*)alloc((size_t)(TG + 1) * 4);
    bf16*  w6    = (bf16*)alloc(6 * TH * TH * 2);
    bf16*  wgru  = (bf16*)alloc(2 * 384 * TH * 2);
    bf16*  wl    = (bf16*)alloc(512 * 256 * 2);
    if (ws_size < off) return;

    bf16* w_gin1_0 = w6;
    bf16* w_gin1_1 = w6 + 1 * TH * TH;
    bf16* w_gin2_0 = w6 + 2 * TH * TH;
    bf16* w_gin2_1 = w6 + 3 * TH * TH;
    bf16* w_em1    = w6 + 4 * TH * TH;
    bf16* w_em2    = w6 + 5 * TH * TH;
    bf16* w_wih    = wgru;
    bf16* w_whh    = wgru + 384 * TH;

    // ---- CSR + gptr ----
    hipMemsetAsync(deg, 0, (size_t)TN * 4, stream);
    hipMemsetAsync(cur, 0, (size_t)TN * 4, stream);
    count_deg<<<(TE + 255) / 256, 256, 0, stream>>>(ei_dst, deg, TE);
    int nb = (TN + 255) / 256;
    scan_block<<<nb, 256, 0, stream>>>(deg, rowptr, bsum, TN);
    scan_bsum<<<1, 512, 0, stream>>>(bsum, bsumx, nb);
    add_off<<<nb, 256, 0, stream>>>(rowptr, bsumx, TN, TE);
    fill_csr<<<(TE + 255) / 256, 256, 0, stream>>>(ei_src, ei_dst, rowptr, cur, srcp, epos, TE);
    build_gptr<<<(TN + 255) / 256, 256, 0, stream>>>(batch, gptr, TN, TG);

    // ---- weights (one merged kernel) ----
    int convTot = 6 * TH * TH + 2 * 384 * TH + 512 * 256;
    convAll<<<(convTot + 255) / 256, 256, 0, stream>>>(
        gin_w1, gin_w2, em_w1, em_w2, gru_wih, gru_whh, lstm_wih, lstm_whh,
        w6, wgru, wl);

    // ---- projections (edges scattered into CSR slot order) ----
    proj64<14><<<(TN + 63) / 64, 256, 0, stream>>>(x, node_w, node_b, (ushort*)nodeb, TN);
    proj_scatter<<<(TE + 63) / 64, 256, 0, stream>>>(edge_attr, edge_w, edge_b,
                                                     epos, (ushort*)e1b, TE);

    const int ntG = (TN + 63) / 64;   // gru tiles

    // ---- layer 0: aggregate -> zb; MLP in-place; GRU ----
    aggregate_v8<<<(TN * 16 + 255) / 256, 256, 0, stream>>>(
        (const ushort*)nodeb, (const ushort*)e1b, srcp, rowptr, eps, 0, (ushort*)zb, TN);
    launch_mlp2(zb, w_gin1_0, gin_b1, w_gin2_0, gin_b2, zb, TN, stream);
    gru_fused<<<512, 512, 0, stream>>>(
        (const ushort*)zb, (const ushort*)w_wih, (const ushort*)w_whh,
        gru_bih, gru_bhh, (ushort*)nodeb, TN, ntG);

    // ---- edge MLP in-place (slot order preserved), layer 1 ----
    launch_mlp2(e1b, w_em1, em_b1, w_em2, em_b2, e1b, TE, stream);
    aggregate_v8<<<(TN * 16 + 255) / 256, 256, 0, stream>>>(
        (const ushort*)nodeb, (const ushort*)e1b, srcp, rowptr, eps, 1, (ushort*)zb, TN);
    launch_mlp2(zb, w_gin1_1, gin_b1 + TH, w_gin2_1, gin_b2 + TH, zb, TN, stream);
    gru_fused<<<512, 512, 0, stream>>>(
        (const ushort*)zb, (const ushort*)w_wih, (const ushort*)w_whh,
        gru_bih, gru_bhh, (ushort*)nodeb, TN, ntG);

    // ---- Set2Set (3 steps) + final FC, fully fused (v2) ----
    set2set_fused<<<(TG + 15) / 16, 256, 0, stream>>>(
        (const ushort*)nodeb, (const ushort*)wl, lstm_bih, lstm_bhh, gptr,
        fc_w1, fc_b1, fc_w2, fc_b2, out, TG);
}

// Round 11
// 524.318 us; speedup vs baseline: 1.0634x; 1.0634x over previous
//
#include <hip/hip_runtime.h>
#include <hip/hip_bf16.h>

constexpr int TN = 100000;   // nodes
constexpr int TE = 200000;   // edges
constexpr int TG = 4000;     // graphs
constexpr int TH = 128;      // hidden

using short8 = __attribute__((ext_vector_type(8))) short;
using f32x4  = __attribute__((ext_vector_type(4))) float;
typedef __hip_bfloat16 bf16;

#define DEVINL __device__ __forceinline__
DEVINL float sigm(float x)  { return 1.f / (1.f + __expf(-x)); }
DEVINL float ftanh(float x) { return 1.f - 2.f / (__expf(2.f * x) + 1.f); }
DEVINL void unpack8(uint4 v, float* f) {
    const ushort* u = (const ushort*)&v;
#pragma unroll
    for (int j = 0; j < 8; ++j) f[j] = __bfloat162float(*(const bf16*)&u[j]);
}

// async global->LDS, 16B per lane; dest = uniform base + lane*16
DEVINL void gload_lds16(const ushort* gsrc, ushort* ldst) {
    __builtin_amdgcn_global_load_lds(
        (const __attribute__((address_space(1))) void*)gsrc,
        (__attribute__((address_space(3))) void*)ldst, 16, 0, 0);
}

// ================= merged weight conversion =================
__global__ void convAll(const float* __restrict__ g1, const float* __restrict__ g2,
                        const float* __restrict__ e1, const float* __restrict__ e2,
                        const float* __restrict__ gwih, const float* __restrict__ gwhh,
                        const float* __restrict__ lwih, const float* __restrict__ lwhh,
                        bf16* __restrict__ w6, bf16* __restrict__ wgru,
                        bf16* __restrict__ wl) {
    int i = blockIdx.x * 256 + threadIdx.x;
    if (i < 6 * TH * TH) {
        int m = i >> 14, r = i & 16383;
        int n = r >> 7, k = r & 127;
        const float* s = (m == 0) ? g1 : (m == 1) ? g1 + TH * TH
                       : (m == 2) ? g2 : (m == 3) ? g2 + TH * TH
                       : (m == 4) ? e1 : e2;
        w6[i] = __float2bfloat16(s[k * TH + n]);
        return;
    }
    i -= 6 * TH * TH;
    if (i < 2 * 384 * TH) {
        const float* s = (i < 384 * TH) ? gwih : gwhh;
        int r = (i < 384 * TH) ? i : i - 384 * TH;
        wgru[i] = __float2bfloat16(s[r]);
        return;
    }
    i -= 2 * 384 * TH;
    if (i < 512 * 256) {
        int c = i >> 8, k = i & 255;
        float v = (k < 128) ? lwih[c * 256 + k] + lwhh[c * 128 + k] : lwih[c * 256 + k];
        wl[i] = __float2bfloat16(v);
    }
}

// ================= node projection: 64 rows/block ============
template<int K>
__global__ __launch_bounds__(256) void proj64(const float* __restrict__ X,
                                              const float* __restrict__ W,
                                              const float* __restrict__ b,
                                              ushort* __restrict__ out, int M) {
    __shared__ float xs[64][K];
    int tid = threadIdx.x;
    int bm = blockIdx.x * 64;
    for (int i = tid; i < 64 * K; i += 256) {
        int r = i / K, k = i % K;
        xs[r][k] = (bm + r < M) ? X[(size_t)(bm + r) * K + k] : 0.f;
    }
    __syncthreads();
    int rb = tid >> 4, h0 = (tid & 15) * 8;
    float acc[4][8];
#pragma unroll
    for (int j = 0; j < 4; ++j)
#pragma unroll
        for (int c = 0; c < 8; ++c) acc[j][c] = b[h0 + c];
#pragma unroll
    for (int k = 0; k < K; ++k) {
        float4 w0 = *(const float4*)(W + k * TH + h0);
        float4 w1 = *(const float4*)(W + k * TH + h0 + 4);
#pragma unroll
        for (int j = 0; j < 4; ++j) {
            float xv = xs[rb + 16 * j][k];
            acc[j][0] = fmaf(xv, w0.x, acc[j][0]); acc[j][1] = fmaf(xv, w0.y, acc[j][1]);
            acc[j][2] = fmaf(xv, w0.z, acc[j][2]); acc[j][3] = fmaf(xv, w0.w, acc[j][3]);
            acc[j][4] = fmaf(xv, w1.x, acc[j][4]); acc[j][5] = fmaf(xv, w1.y, acc[j][5]);
            acc[j][6] = fmaf(xv, w1.z, acc[j][6]); acc[j][7] = fmaf(xv, w1.w, acc[j][7]);
        }
    }
#pragma unroll
    for (int j = 0; j < 4; ++j) {
        int row = bm + rb + 16 * j;
        if (row >= M) continue;
        ushort o[8];
#pragma unroll
        for (int c = 0; c < 8; ++c) {
            bf16 v = __float2bfloat16(acc[j][c]);
            o[c] = *(ushort*)&v;
        }
        *(uint4*)(out + (size_t)row * TH + h0) = *(uint4*)o;
    }
}

// ===== proj_scatter: K=4 projection with CSR-slot scatter (layer-0 e0) =====
__global__ __launch_bounds__(256) void proj_scatter(
    const float* __restrict__ X, const float* __restrict__ W,
    const float* __restrict__ b, const int* __restrict__ perm,
    ushort* __restrict__ out, int M) {
    __shared__ float xs[64][4];
    int tid = threadIdx.x;
    int bm = blockIdx.x * 64;
    if (tid < 64) {
        float4 a = make_float4(0.f, 0.f, 0.f, 0.f);
        if (bm + tid < M) a = *(const float4*)(X + (size_t)(bm + tid) * 4);
        xs[tid][0] = a.x; xs[tid][1] = a.y; xs[tid][2] = a.z; xs[tid][3] = a.w;
    }
    __syncthreads();
    int rb = tid >> 4, h0 = (tid & 15) * 8;
    float acc[4][8];
#pragma unroll
    for (int j = 0; j < 4; ++j)
#pragma unroll
        for (int c = 0; c < 8; ++c) acc[j][c] = b[h0 + c];
#pragma unroll
    for (int k = 0; k < 4; ++k) {
        float4 w0 = *(const float4*)(W + k * TH + h0);
        float4 w1 = *(const float4*)(W + k * TH + h0 + 4);
#pragma unroll
        for (int j = 0; j < 4; ++j) {
            float xv = xs[rb + 16 * j][k];
            acc[j][0] = fmaf(xv, w0.x, acc[j][0]); acc[j][1] = fmaf(xv, w0.y, acc[j][1]);
            acc[j][2] = fmaf(xv, w0.z, acc[j][2]); acc[j][3] = fmaf(xv, w0.w, acc[j][3]);
            acc[j][4] = fmaf(xv, w1.x, acc[j][4]); acc[j][5] = fmaf(xv, w1.y, acc[j][5]);
            acc[j][6] = fmaf(xv, w1.z, acc[j][6]); acc[j][7] = fmaf(xv, w1.w, acc[j][7]);
        }
    }
#pragma unroll
    for (int j = 0; j < 4; ++j) {
        int row = bm + rb + 16 * j;
        if (row >= M) continue;
        ushort o[8];
#pragma unroll
        for (int c = 0; c < 8; ++c) {
            bf16 v = __float2bfloat16(acc[j][c]);
            o[c] = *(ushort*)&v;
        }
        *(uint4*)(out + (size_t)perm[row] * TH + h0) = *(uint4*)o;
    }
}

// ================= CSR build =================
__global__ void count_deg(const int* __restrict__ ei_dst, int* __restrict__ deg, int En) {
    int e = blockIdx.x * 256 + threadIdx.x;
    if (e < En) atomicAdd(&deg[ei_dst[e]], 1);
}
__global__ void scan_block(const int* __restrict__ deg, int* __restrict__ rowptr,
                           int* __restrict__ bsum, int Nn) {
    __shared__ int sm[256];
    int tid = threadIdx.x;
    int gid = blockIdx.x * 256 + tid;
    int v = (gid < Nn) ? deg[gid] : 0;
    int x = v;
    sm[tid] = x; __syncthreads();
    for (int off = 1; off < 256; off <<= 1) {
        int t = (tid >= off) ? sm[tid - off] : 0;
        __syncthreads();
        x += t; sm[tid] = x;
        __syncthreads();
    }
    if (gid < Nn) rowptr[gid] = x - v;
    if (tid == 255) bsum[blockIdx.x] = x;
}
__global__ void scan_bsum(const int* __restrict__ bsum, int* __restrict__ bsumx, int nb) {
    __shared__ int sm[512];
    int tid = threadIdx.x;
    int v = (tid < nb) ? bsum[tid] : 0;
    int x = v;
    sm[tid] = x; __syncthreads();
    for (int off = 1; off < 512; off <<= 1) {
        int t = (tid >= off) ? sm[tid - off] : 0;
        __syncthreads();
        x += t; sm[tid] = x;
        __syncthreads();
    }
    if (tid < nb) bsumx[tid] = x - v;
}
__global__ void add_off(int* __restrict__ rowptr, const int* __restrict__ bsumx,
                        int Nn, int Etot) {
    int gid = blockIdx.x * 256 + threadIdx.x;
    if (gid < Nn) rowptr[gid] += bsumx[gid >> 8];
    if (gid == 0) rowptr[Nn] = Etot;
}
__global__ void fill_csr(const int* __restrict__ ei_src, const int* __restrict__ ei_dst,
                         const int* __restrict__ rowptr, int* __restrict__ cur,
                         int* __restrict__ srcp, int* __restrict__ epos, int En) {
    int e = blockIdx.x * 256 + threadIdx.x;
    if (e >= En) return;
    int d = ei_dst[e];
    int p = atomicAdd(&cur[d], 1);
    int slot = rowptr[d] + p;
    srcp[slot] = ei_src[e];
    epos[e] = slot;
}
__global__ void build_gptr(const int* __restrict__ batch, int* __restrict__ gptr,
                           int Nn, int Gn) {
    int n = blockIdx.x * 256 + threadIdx.x;
    if (n >= Nn) return;
    int bc = batch[n];
    int bp = (n == 0) ? -1 : batch[n - 1];
    for (int g = bp + 1; g <= bc; ++g) gptr[g] = n;
    if (n == Nn - 1) for (int g = bc + 1; g <= Gn; ++g) gptr[g] = Nn;
}

// ========== aggregation, 16 threads/node, 8 ch/thread, 2-way unroll ==========
__global__ __launch_bounds__(256) void aggregate_v8(
    const ushort* __restrict__ node, const ushort* __restrict__ ef,
    const int* __restrict__ srcp, const int* __restrict__ rowptr,
    const float* __restrict__ eps, int l, ushort* __restrict__ zb, int Nn) {
    int t = blockIdx.x * 256 + threadIdx.x;
    int n = t >> 4;
    if (n >= Nn) return;
    int c8 = (t & 15) * 8;
    float se = 1.f + eps[l];
    float acc[8];
    uint4 nv = *(const uint4*)(node + (size_t)n * TH + c8);
    unpack8(nv, acc);
#pragma unroll
    for (int j = 0; j < 8; ++j) acc[j] *= se;
    int s0 = rowptr[n], s1 = rowptr[n + 1];
    int i = s0;
    for (; i + 1 < s1; i += 2) {
        int sa = srcp[i], sb = srcp[i + 1];
        uint4 av0 = *(const uint4*)(node + (size_t)sa * TH + c8);
        uint4 bv0 = *(const uint4*)(ef + (size_t)i * TH + c8);
        uint4 av1 = *(const uint4*)(node + (size_t)sb * TH + c8);
        uint4 bv1 = *(const uint4*)(ef + (size_t)(i + 1) * TH + c8);
        float a0[8], b0[8], a1[8], b1[8];
        unpack8(av0, a0); unpack8(bv0, b0);
        unpack8(av1, a1); unpack8(bv1, b1);
#pragma unroll
        for (int j = 0; j < 8; ++j)
            acc[j] += fmaxf(a0[j] + b0[j], 0.f) + fmaxf(a1[j] + b1[j], 0.f);
    }
    if (i < s1) {
        int sa = srcp[i];
        uint4 av = *(const uint4*)(node + (size_t)sa * TH + c8);
        uint4 bv = *(const uint4*)(ef + (size_t)i * TH + c8);
        float af[8], bf[8];
        unpack8(av, af); unpack8(bv, bf);
#pragma unroll
        for (int j = 0; j < 8; ++j) acc[j] += fmaxf(af[j] + bf[j], 0.f);
    }
    ushort o[8];
#pragma unroll
    for (int j = 0; j < 8; ++j) {
        bf16 v = __float2bfloat16(acc[j]);
        o[j] = *(ushort*)&v;
    }
    *(uint4*)(zb + (size_t)n * TH + c8) = *(uint4*)o;
}

// ===== fused 2-layer MLP (R5/R7 form): one tile per block, single 32 KB LDS =====
__global__ __launch_bounds__(256, 2) void mlp2_fused(
    const ushort* __restrict__ A, const ushort* __restrict__ W1t,
    const float* __restrict__ b1, const ushort* __restrict__ W2t,
    const float* __restrict__ b2, ushort* __restrict__ C, int M)
{
    __shared__ ushort As[128 * 128];
    const int tid = threadIdx.x;
    const int bm = blockIdx.x * 128;
    const int lane = tid & 63, w = tid >> 6;
    const int lr = lane & 15, lq = lane >> 4;
    const int wm = (w & 1) * 64, wn = (w >> 1) * 64;
    short8 wf[4][4];
#pragma unroll
    for (int ni = 0; ni < 4; ++ni)
#pragma unroll
        for (int ks = 0; ks < 4; ++ks)
            wf[ni][ks] = *(const short8*)(W1t + (size_t)(wn + ni * 16 + lr) * 128 + ks * 32 + lq * 8);
    // async staging: wave w covers slots [w*512, w*512+512)
#pragma unroll
    for (int i = 0; i < 8; ++i) {
        int s = w * 512 + i * 64 + lane;
        int r = s >> 4;
        int c = (s & 15) ^ (r & 15);
        gload_lds16(A + (size_t)(bm + r) * 128 + c * 8, As + (w * 512 + i * 64) * 8);
    }
    __syncthreads();
    f32x4 acc[4][4] = {};
#pragma unroll
    for (int ks = 0; ks < 4; ++ks) {
        int cb = ks * 4 + lq;
        short8 af[4];
#pragma unroll
        for (int mi = 0; mi < 4; ++mi)
            af[mi] = *(const short8*)(&As[(wm + mi * 16 + lr) * 128 + ((cb ^ lr) * 8)]);
#pragma unroll
        for (int mi = 0; mi < 4; ++mi)
#pragma unroll
            for (int ni = 0; ni < 4; ++ni)
                acc[mi][ni] = __builtin_amdgcn_mfma_f32_16x16x32_bf16(af[mi], wf[ni][ks], acc[mi][ni], 0, 0, 0);
    }
    __syncthreads();   // all As reads complete before in-place T write
#pragma unroll
    for (int mi = 0; mi < 4; ++mi)
#pragma unroll
        for (int reg = 0; reg < 4; ++reg) {
            int row = wm + mi * 16 + lq * 4 + reg;
#pragma unroll
            for (int ni = 0; ni < 4; ++ni) {
                int col = wn + ni * 16 + lr;
                float v = fmaxf(acc[mi][ni][reg] + b1[col], 0.f);
                bf16 bv = __float2bfloat16(v);
                As[row * 128 + (((col >> 3) ^ (row & 15)) * 8) + (col & 7)] = *(ushort*)&bv;
            }
        }
    // preload W2 (independent of LDS; latency hides under barrier)
#pragma unroll
    for (int ni = 0; ni < 4; ++ni)
#pragma unroll
        for (int ks = 0; ks < 4; ++ks)
            wf[ni][ks] = *(const short8*)(W2t + (size_t)(wn + ni * 16 + lr) * 128 + ks * 32 + lq * 8);
    __syncthreads();
    {
        f32x4 acc2[4][4] = {};
#pragma unroll
        for (int ks = 0; ks < 4; ++ks) {
            int cb = ks * 4 + lq;
            short8 af[4];
#pragma unroll
            for (int mi = 0; mi < 4; ++mi)
                af[mi] = *(const short8*)(&As[(wm + mi * 16 + lr) * 128 + ((cb ^ lr) * 8)]);
#pragma unroll
            for (int mi = 0; mi < 4; ++mi)
#pragma unroll
                for (int ni = 0; ni < 4; ++ni)
                    acc2[mi][ni] = __builtin_amdgcn_mfma_f32_16x16x32_bf16(af[mi], wf[ni][ks], acc2[mi][ni], 0, 0, 0);
        }
#pragma unroll
        for (int mi = 0; mi < 4; ++mi)
#pragma unroll
            for (int reg = 0; reg < 4; ++reg) {
                int row = bm + wm + mi * 16 + lq * 4 + reg;
                if (row >= M) continue;
#pragma unroll
                for (int ni = 0; ni < 4; ++ni) {
                    int col = wn + ni * 16 + lr;
                    bf16 bv = __float2bfloat16(acc2[mi][ni][reg] + b2[col]);
                    C[(size_t)row * 128 + col] = *(ushort*)&bv;
                }
            }
    }
}

// ===== fused GRU v6 (R8 proven): weight-stationary, dbuf, counted vmcnt, grid 512 =====
__global__ __launch_bounds__(512, 2) void gru_fused(
    const ushort* __restrict__ mfeat, const ushort* __restrict__ wih,
    const ushort* __restrict__ whh, const float* __restrict__ bih,
    const float* __restrict__ bhh, ushort* __restrict__ node, int Nn, int nT)
{
    __shared__ ushort Ms[2][64 * 128];
    __shared__ ushort Hs[2][64 * 128];
    const int tid = threadIdx.x;
    const int lane = tid & 63, w = tid >> 6;
    const int lr = lane & 15, lq = lane >> 4;
    const int col = w * 16 + lr;
    short8 W[6][4];
#pragma unroll
    for (int ks = 0; ks < 4; ++ks) {
        int koff = ks * 32 + lq * 8;
        W[0][ks] = *(const short8*)(wih + (size_t)col * 128 + koff);
        W[1][ks] = *(const short8*)(wih + (size_t)(128 + col) * 128 + koff);
        W[2][ks] = *(const short8*)(wih + (size_t)(256 + col) * 128 + koff);
        W[3][ks] = *(const short8*)(whh + (size_t)col * 128 + koff);
        W[4][ks] = *(const short8*)(whh + (size_t)(128 + col) * 128 + koff);
        W[5][ks] = *(const short8*)(whh + (size_t)(256 + col) * 128 + koff);
    }
    const float br  = bih[col] + bhh[col];
    const float bz  = bih[128 + col] + bhh[128 + col];
    const float bin = bih[256 + col], bhn = bhh[256 + col];

    auto stage = [&](int tt, int buf) {
#pragma unroll
        for (int i = 0; i < 2; ++i) {
            int sb = w * 128 + i * 64;
            int s = sb + lane;
            int r = s >> 4;
            int c = (s & 15) ^ (r & 15);
            size_t goff = (size_t)(tt * 64 + r) * 128 + c * 8;
            gload_lds16(mfeat + goff, &Ms[buf][sb * 8]);
            gload_lds16(node + goff, &Hs[buf][sb * 8]);
        }
    };

    int t = blockIdx.x;
    const int G = gridDim.x;
    if (t >= nT) return;
    stage(t, 0);
    int cur = 0;
    while (t < nT) {
        int tn = t + G;
        if (tn < nT) {
            stage(tn, cur ^ 1);
            asm volatile("s_waitcnt vmcnt(4)" ::: "memory");
        } else {
            asm volatile("s_waitcnt vmcnt(0)" ::: "memory");
        }
        __builtin_amdgcn_sched_barrier(0);
        __builtin_amdgcn_s_barrier();
        __builtin_amdgcn_sched_barrier(0);
        {
            const ushort* Mc = Ms[cur];
            const ushort* Hc = Hs[cur];
            f32x4 aR[4] = {}, aZ[4] = {}, aN[4] = {}, aH[4] = {};
#pragma unroll
            for (int ks = 0; ks < 4; ++ks) {
                int cb = ks * 4 + lq;
#pragma unroll
                for (int rt = 0; rt < 4; ++rt) {
                    int off = (rt * 16 + lr) * 128 + ((cb ^ lr) * 8);
                    short8 am = *(const short8*)(&Mc[off]);
                    short8 ah = *(const short8*)(&Hc[off]);
                    aR[rt] = __builtin_amdgcn_mfma_f32_16x16x32_bf16(am, W[0][ks], aR[rt], 0, 0, 0);
                    aR[rt] = __builtin_amdgcn_mfma_f32_16x16x32_bf16(ah, W[3][ks], aR[rt], 0, 0, 0);
                    aZ[rt] = __builtin_amdgcn_mfma_f32_16x16x32_bf16(am, W[1][ks], aZ[rt], 0, 0, 0);
                    aZ[rt] = __builtin_amdgcn_mfma_f32_16x16x32_bf16(ah, W[4][ks], aZ[rt], 0, 0, 0);
                    aN[rt] = __builtin_amdgcn_mfma_f32_16x16x32_bf16(am, W[2][ks], aN[rt], 0, 0, 0);
                    aH[rt] = __builtin_amdgcn_mfma_f32_16x16x32_bf16(ah, W[5][ks], aH[rt], 0, 0, 0);
                }
            }
            const int bm = t * 64;
#pragma unroll
            for (int rt = 0; rt < 4; ++rt)
#pragma unroll
                for (int reg = 0; reg < 4; ++reg) {
                    int lrow = rt * 16 + lq * 4 + reg;
                    int row = bm + lrow;
                    if (row >= Nn) continue;
                    float r = sigm(aR[rt][reg] + br);
                    float z = sigm(aZ[rt][reg] + bz);
                    float n = ftanh(aN[rt][reg] + bin + r * (aH[rt][reg] + bhn));
                    int hofs = lrow * 128 + (((col >> 3) ^ (lrow & 15)) * 8) + (col & 7);
                    float hold = __bfloat162float(*(const bf16*)&Hc[hofs]);
                    bf16 hv = __float2bfloat16((1.f - z) * n + z * hold);
                    node[(size_t)row * 128 + col] = *(ushort*)&hv;
                }
        }
        __builtin_amdgcn_sched_barrier(0);
        __builtin_amdgcn_s_barrier();
        __builtin_amdgcn_sched_barrier(0);
        cur ^= 1;
        t = tn;
    }
}

// ================= fused LSTM step (16 graphs/block) =================
__global__ __launch_bounds__(256) void lstm_fused(
    ushort* __restrict__ s, const ushort* __restrict__ Wl,
    const float* __restrict__ bih, const float* __restrict__ bhh,
    float* __restrict__ cl, int Gn)
{
    __shared__ ushort Ss[16 * 256];
    const int tid = threadIdx.x;
    const int bm = blockIdx.x * 16;
#pragma unroll
    for (int p = 0; p < 2; ++p) {
        int ch = p * 256 + tid;
        int r = ch >> 5, c = ch & 31;
        int row = bm + r;
        uint4 v = make_uint4(0u, 0u, 0u, 0u);
        if (row < Gn) v = *(const uint4*)(s + (size_t)row * 256 + c * 8);
        *(uint4*)(&Ss[r * 256 + ((c ^ (r & 15)) * 8)]) = v;
    }
    __syncthreads();
    const int lane = tid & 63, w = tid >> 6;
    const int lr = lane & 15, lq = lane >> 4;
    f32x4 acc[4][2] = {};
#pragma unroll
    for (int ks = 0; ks < 8; ++ks) {
        int cb = ks * 4 + lq;
        short8 am = *(const short8*)(&Ss[lr * 256 + ((cb ^ lr) * 8)]);
        int koff = ks * 32 + lq * 8;
#pragma unroll
        for (int g = 0; g < 4; ++g)
#pragma unroll
            for (int sub = 0; sub < 2; ++sub) {
                int col = g * 128 + w * 32 + sub * 16 + lr;
                short8 bf = *(const short8*)(Wl + (size_t)col * 256 + koff);
                acc[g][sub] = __builtin_amdgcn_mfma_f32_16x16x32_bf16(am, bf, acc[g][sub], 0, 0, 0);
            }
    }
#pragma unroll
    for (int sub = 0; sub < 2; ++sub) {
        int h = w * 32 + sub * 16 + lr;
        float bi = bih[h] + bhh[h];
        float bff = bih[128 + h] + bhh[128 + h];
        float bg = bih[256 + h] + bhh[256 + h];
        float bo = bih[384 + h] + bhh[384 + h];
#pragma unroll
        for (int reg = 0; reg < 4; ++reg) {
            int row = bm + lq * 4 + reg;
            if (row >= Gn) continue;
            float iv = sigm(acc[0][sub][reg] + bi);
            float fv = sigm(acc[1][sub][reg] + bff);
            float gv = ftanh(acc[2][sub][reg] + bg);
            float ov = sigm(acc[3][sub][reg] + bo);
            float c = fv * cl[(size_t)row * 128 + h] + iv * gv;
            cl[(size_t)row * 128 + h] = c;
            bf16 hv = __float2bfloat16(ov * ftanh(c));
            s[(size_t)row * 256 + h] = *(ushort*)&hv;
        }
    }
}

// ================= fused per-graph attention (vectorized, no reg cache) =========
__global__ __launch_bounds__(256) void att_fused(
    const ushort* __restrict__ node, ushort* __restrict__ s,
    const int* __restrict__ gptr)
{
    __shared__ float q[128];
    __shared__ float es[512];
    __shared__ float red[8];
    __shared__ float part[16][128];
    int g = blockIdx.x;
    int tid = threadIdx.x, lane = tid & 63, wid = tid >> 6;
    int n0 = gptr[g], n1 = gptr[g + 1];
    int cnt = n1 - n0; if (cnt > 512) cnt = 512;
    if (tid < 128) q[tid] = __bfloat162float(((const bf16*)s)[(size_t)g * 256 + tid]);
    __syncthreads();
    int gr = tid >> 4, c8 = (tid & 15) * 8;
    for (int i0 = 0; i0 < cnt; i0 += 16) {
        int i = i0 + gr;
        float p = 0.f;
        if (i < cnt) {
            uint4 v = *(const uint4*)(node + (size_t)(n0 + i) * TH + c8);
            float f[8]; unpack8(v, f);
#pragma unroll
            for (int j = 0; j < 8; ++j) p = fmaf(f[j], q[c8 + j], p);
        }
        p += __shfl_down(p, 8, 16);
        p += __shfl_down(p, 4, 16);
        p += __shfl_down(p, 2, 16);
        p += __shfl_down(p, 1, 16);
        if ((tid & 15) == 0 && i < cnt) es[i] = p;
    }
    __syncthreads();
    float m = -1e30f;
    for (int i = tid; i < cnt; i += 256) m = fmaxf(m, es[i]);
    for (int off = 32; off; off >>= 1) m = fmaxf(m, __shfl_down(m, off));
    if (lane == 0) red[wid] = m;
    __syncthreads();
    m = fmaxf(fmaxf(red[0], red[1]), fmaxf(red[2], red[3]));
    float sm = 0.f;
    for (int i = tid; i < cnt; i += 256) { float ex = __expf(es[i] - m); es[i] = ex; sm += ex; }
    for (int off = 32; off; off >>= 1) sm += __shfl_down(sm, off);
    if (lane == 0) red[4 + wid] = sm;
    __syncthreads();
    sm = red[4] + red[5] + red[6] + red[7];
    float inv = 1.f / fmaxf(sm, 1e-9f);
    float racc[8] = {};
    for (int i = gr; i < cnt; i += 16) {
        uint4 v = *(const uint4*)(node + (size_t)(n0 + i) * TH + c8);
        float f[8]; unpack8(v, f);
        float a = es[i];
#pragma unroll
        for (int j = 0; j < 8; ++j) racc[j] = fmaf(a, f[j], racc[j]);
    }
#pragma unroll
    for (int j = 0; j < 8; ++j) part[gr][c8 + j] = racc[j];
    __syncthreads();
    if (tid < 128) {
        float r = 0.f;
#pragma unroll
        for (int k = 0; k < 16; ++k) r += part[k][tid];
        bf16 rv = __float2bfloat16(r * inv);
        s[(size_t)g * 256 + 128 + tid] = *(ushort*)&rv;
    }
}

// ================= final FC =================
__global__ __launch_bounds__(128) void final_fc(const ushort* __restrict__ s,
                                                const float* __restrict__ w1,
                                                const float* __restrict__ b1,
                                                const float* __restrict__ w2,
                                                const float* __restrict__ b2,
                                                float* __restrict__ out) {
    __shared__ float q[256];
    __shared__ float red[2];
    int g = blockIdx.x, t = threadIdx.x;
    q[t] = __bfloat162float(((const bf16*)s)[(size_t)g * 256 + t]);
    q[t + 128] = __bfloat162float(((const bf16*)s)[(size_t)g * 256 + 128 + t]);
    __syncthreads();
    float acc = b1[t];
    for (int k = 0; k < 256; ++k) acc = fmaf(q[k], w1[k * TH + t], acc);
    acc = fmaxf(acc, 0.f);
    float p = acc * w2[t];
    for (int off = 32; off; off >>= 1) p += __shfl_down(p, off);
    if ((t & 63) == 0) red[t >> 6] = p;
    __syncthreads();
    if (t == 0) out[g] = red[0] + red[1] + b2[0];
}

// ---------------------------------------------------------------------------
static void launch_mlp2(const void* A, const bf16* W1t, const float* b1,
                        const bf16* W2t, const float* b2, void* C, int M, hipStream_t s) {
    hipLaunchKernelGGL(mlp2_fused, dim3((M + 127) / 128), dim3(256), 0, s,
                       (const ushort*)A, (const ushort*)W1t, b1, (const ushort*)W2t, b2,
                       (ushort*)C, M);
}

extern "C" void kernel_launch(void* const* d_in, const int* in_sizes, int n_in,
                              void* d_out, int out_size, void* d_ws, size_t ws_size,
                              hipStream_t stream) {
    const float* x         = (const float*)d_in[0];
    const float* edge_attr = (const float*)d_in[1];
    const int*   edge_index= (const int*)d_in[2];
    const int*   batch     = (const int*)d_in[3];
    const float* node_w    = (const float*)d_in[4];
    const float* node_b    = (const float*)d_in[5];
    const float* edge_w    = (const float*)d_in[6];
    const float* edge_b    = (const float*)d_in[7];
    const float* eps       = (const float*)d_in[8];
    const float* gin_w1    = (const float*)d_in[9];
    const float* gin_b1    = (const float*)d_in[10];
    const float* gin_w2    = (const float*)d_in[11];
    const float* gin_b2    = (const float*)d_in[12];
    const float* em_w1     = (const float*)d_in[13];
    const float* em_b1     = (const float*)d_in[14];
    const float* em_w2     = (const float*)d_in[15];
    const float* em_b2     = (const float*)d_in[16];
    const float* gru_wih   = (const float*)d_in[17];
    const float* gru_whh   = (const float*)d_in[18];
    const float* gru_bih   = (const float*)d_in[19];
    const float* gru_bhh   = (const float*)d_in[20];
    const float* lstm_wih  = (const float*)d_in[21];
    const float* lstm_whh  = (const float*)d_in[22];
    const float* lstm_bih  = (const float*)d_in[23];
    const float* lstm_bhh  = (const float*)d_in[24];
    const float* fc_w1     = (const float*)d_in[25];
    const float* fc_b1     = (const float*)d_in[26];
    const float* fc_w2     = (const float*)d_in[27];
    const float* fc_b2     = (const float*)d_in[28];
    float* out = (float*)d_out;
    const int* ei_src = edge_index;
    const int* ei_dst = edge_index + TE;

    // ---- workspace layout ----
    char* base = (char*)d_ws;
    size_t off = 0;
    auto alloc = [&](size_t bytes) { void* p = base + off; off += (bytes + 15) & ~size_t(15); return p; };
    bf16*  nodeb = (bf16*)alloc((size_t)TN * TH * 2);   // 25.6 MB
    bf16*  zb    = (bf16*)alloc((size_t)TN * TH * 2);   // 25.6 MB
    bf16*  e1b   = (bf16*)alloc((size_t)TE * TH * 2);   // 51.2 MB (set2set overlay later)
    int*   deg   = (int*)alloc((size_t)TN * 4);
    int*   rowptr= (int*)alloc((size_t)(TN + 1) * 4);
    int*   cur   = (int*)alloc((size_t)TN * 4);
    int*   srcp  = (int*)alloc((size_t)TE * 4);
    int*   epos  = (int*)alloc((size_t)TE * 4);
    int*   bsum  = (int*)alloc(512 * 4);
    int*   bsumx = (int*)alloc(512 * 4);
    int*   gptr  = (int*)alloc((size_t)(TG + 1) * 4);
    bf16*  w6    = (bf16*)alloc(6 * TH * TH * 2);
    bf16*  wgru  = (bf16*)alloc(2 * 384 * TH * 2);
    bf16*  wl    = (bf16*)alloc(512 * 256 * 2);
    if (ws_size < off) return;

    bf16* w_gin1_0 = w6;
    bf16* w_gin1_1 = w6 + 1 * TH * TH;
    bf16* w_gin2_0 = w6 + 2 * TH * TH;
    bf16* w_gin2_1 = w6 + 3 * TH * TH;
    bf16* w_em1    = w6 + 4 * TH * TH;
    bf16* w_em2    = w6 + 5 * TH * TH;
    bf16* w_wih    = wgru;
    bf16* w_whh    = wgru + 384 * TH;

    ushort* sbuf = (ushort*)e1b;                      // [G][256] bf16
    float*  cl   = (float*)(sbuf + (size_t)TG * 256); // [G][128] fp32

    // ---- CSR + gptr ----
    hipMemsetAsync(deg, 0, (size_t)TN * 4, stream);
    hipMemsetAsync(cur, 0, (size_t)TN * 4, stream);
    count_deg<<<(TE + 255) / 256, 256, 0, stream>>>(ei_dst, deg, TE);
    int nb = (TN + 255) / 256;
    scan_block<<<nb, 256, 0, stream>>>(deg, rowptr, bsum, TN);
    scan_bsum<<<1, 512, 0, stream>>>(bsum, bsumx, nb);
    add_off<<<nb, 256, 0, stream>>>(rowptr, bsumx, TN, TE);
    fill_csr<<<(TE + 255) / 256, 256, 0, stream>>>(ei_src, ei_dst, rowptr, cur, srcp, epos, TE);
    build_gptr<<<(TN + 255) / 256, 256, 0, stream>>>(batch, gptr, TN, TG);

    // ---- weights (one merged kernel) ----
    int convTot = 6 * TH * TH + 2 * 384 * TH + 512 * 256;
    convAll<<<(convTot + 255) / 256, 256, 0, stream>>>(
        gin_w1, gin_w2, em_w1, em_w2, gru_wih, gru_whh, lstm_wih, lstm_whh,
        w6, wgru, wl);

    // ---- projections (edges scattered into CSR slot order) ----
    proj64<14><<<(TN + 63) / 64, 256, 0, stream>>>(x, node_w, node_b, (ushort*)nodeb, TN);
    proj_scatter<<<(TE + 63) / 64, 256, 0, stream>>>(edge_attr, edge_w, edge_b,
                                                     epos, (ushort*)e1b, TE);

    const int ntG = (TN + 63) / 64;   // gru tiles

    // ---- layer 0: aggregate -> zb; MLP in-place; GRU ----
    aggregate_v8<<<(TN * 16 + 255) / 256, 256, 0, stream>>>(
        (const ushort*)nodeb, (const ushort*)e1b, srcp, rowptr, eps, 0, (ushort*)zb, TN);
    launch_mlp2(zb, w_gin1_0, gin_b1, w_gin2_0, gin_b2, zb, TN, stream);
    gru_fused<<<512, 512, 0, stream>>>(
        (const ushort*)zb, (const ushort*)w_wih, (const ushort*)w_whh,
        gru_bih, gru_bhh, (ushort*)nodeb, TN, ntG);

    // ---- edge MLP in-place (slot order preserved), layer 1 ----
    launch_mlp2(e1b, w_em1, em_b1, w_em2, em_b2, e1b, TE, stream);
    aggregate_v8<<<(TN * 16 + 255) / 256, 256, 0, stream>>>(
        (const ushort*)nodeb, (const ushort*)e1b, srcp, rowptr, eps, 1, (ushort*)zb, TN);
    launch_mlp2(zb, w_gin1_1, gin_b1 + TH, w_gin2_1, gin_b2 + TH, zb, TN, stream);
    gru_fused<<<512, 512, 0, stream>>>(
        (const ushort*)zb, (const ushort*)w_wih, (const ushort*)w_whh,
        gru_bih, gru_bhh, (ushort*)nodeb, TN, ntG);

    // ---- Set2Set (3 steps) ----
    hipMemsetAsync(sbuf, 0, (size_t)TG * 256 * 2 + (size_t)TG * 128 * 4, stream);
    for (int st = 0; st < 3; ++st) {
        lstm_fused<<<(TG + 15) / 16, 256, 0, stream>>>(
            sbuf, (const ushort*)wl, lstm_bih, lstm_bhh, cl, TG);
        att_fused<<<TG, 256, 0, stream>>>((const ushort*)nodeb, sbuf, gptr);
    }

    // ---- final FC ----
    final_fc<<<TG, 128, 0, stream>>>(sbuf, fc_w1, fc_b1, fc_w2, fc_b2, out);
}

// Round 12
// 516.467 us; speedup vs baseline: 1.0796x; 1.0152x over previous
//
#include <hip/hip_runtime.h>
#include <hip/hip_bf16.h>

constexpr int TN = 100000;   // nodes
constexpr int TE = 200000;   // edges
constexpr int TG = 4000;     // graphs
constexpr int TH = 128;      // hidden

using short8 = __attribute__((ext_vector_type(8))) short;
using f32x4  = __attribute__((ext_vector_type(4))) float;
typedef __hip_bfloat16 bf16;

#define DEVINL __device__ __forceinline__
DEVINL float sigm(float x)  { return 1.f / (1.f + __expf(-x)); }
DEVINL float ftanh(float x) { return 1.f - 2.f / (__expf(2.f * x) + 1.f); }
DEVINL void unpack8(uint4 v, float* f) {
    const ushort* u = (const ushort*)&v;
#pragma unroll
    for (int j = 0; j < 8; ++j) f[j] = __bfloat162float(*(const bf16*)&u[j]);
}

// async global->LDS, 16B per lane; dest = uniform base + lane*16
DEVINL void gload_lds16(const ushort* gsrc, ushort* ldst) {
    __builtin_amdgcn_global_load_lds(
        (const __attribute__((address_space(1))) void*)gsrc,
        (__attribute__((address_space(3))) void*)ldst, 16, 0, 0);
}

// ================= merged weight conversion =================
__global__ void convAll(const float* __restrict__ g1, const float* __restrict__ g2,
                        const float* __restrict__ e1, const float* __restrict__ e2,
                        const float* __restrict__ gwih, const float* __restrict__ gwhh,
                        const float* __restrict__ lwih, const float* __restrict__ lwhh,
                        bf16* __restrict__ w6, bf16* __restrict__ wgru,
                        bf16* __restrict__ wl) {
    int i = blockIdx.x * 256 + threadIdx.x;
    if (i < 6 * TH * TH) {
        int m = i >> 14, r = i & 16383;
        int n = r >> 7, k = r & 127;
        const float* s = (m == 0) ? g1 : (m == 1) ? g1 + TH * TH
                       : (m == 2) ? g2 : (m == 3) ? g2 + TH * TH
                       : (m == 4) ? e1 : e2;
        w6[i] = __float2bfloat16(s[k * TH + n]);
        return;
    }
    i -= 6 * TH * TH;
    if (i < 2 * 384 * TH) {
        const float* s = (i < 384 * TH) ? gwih : gwhh;
        int r = (i < 384 * TH) ? i : i - 384 * TH;
        wgru[i] = __float2bfloat16(s[r]);
        return;
    }
    i -= 2 * 384 * TH;
    if (i < 512 * 256) {
        int c = i >> 8, k = i & 255;
        float v = (k < 128) ? lwih[c * 256 + k] + lwhh[c * 128 + k] : lwih[c * 256 + k];
        wl[i] = __float2bfloat16(v);
    }
}

// ================= node projection: 64 rows/block ============
template<int K>
__global__ __launch_bounds__(256) void proj64(const float* __restrict__ X,
                                              const float* __restrict__ W,
                                              const float* __restrict__ b,
                                              ushort* __restrict__ out, int M) {
    __shared__ float xs[64][K];
    int tid = threadIdx.x;
    int bm = blockIdx.x * 64;
    for (int i = tid; i < 64 * K; i += 256) {
        int r = i / K, k = i % K;
        xs[r][k] = (bm + r < M) ? X[(size_t)(bm + r) * K + k] : 0.f;
    }
    __syncthreads();
    int rb = tid >> 4, h0 = (tid & 15) * 8;
    float acc[4][8];
#pragma unroll
    for (int j = 0; j < 4; ++j)
#pragma unroll
        for (int c = 0; c < 8; ++c) acc[j][c] = b[h0 + c];
#pragma unroll
    for (int k = 0; k < K; ++k) {
        float4 w0 = *(const float4*)(W + k * TH + h0);
        float4 w1 = *(const float4*)(W + k * TH + h0 + 4);
#pragma unroll
        for (int j = 0; j < 4; ++j) {
            float xv = xs[rb + 16 * j][k];
            acc[j][0] = fmaf(xv, w0.x, acc[j][0]); acc[j][1] = fmaf(xv, w0.y, acc[j][1]);
            acc[j][2] = fmaf(xv, w0.z, acc[j][2]); acc[j][3] = fmaf(xv, w0.w, acc[j][3]);
            acc[j][4] = fmaf(xv, w1.x, acc[j][4]); acc[j][5] = fmaf(xv, w1.y, acc[j][5]);
            acc[j][6] = fmaf(xv, w1.z, acc[j][6]); acc[j][7] = fmaf(xv, w1.w, acc[j][7]);
        }
    }
#pragma unroll
    for (int j = 0; j < 4; ++j) {
        int row = bm + rb + 16 * j;
        if (row >= M) continue;
        ushort o[8];
#pragma unroll
        for (int c = 0; c < 8; ++c) {
            bf16 v = __float2bfloat16(acc[j][c]);
            o[c] = *(ushort*)&v;
        }
        *(uint4*)(out + (size_t)row * TH + h0) = *(uint4*)o;
    }
}

// ===== proj_scatter: K=4 projection with CSR-slot scatter (layer-0 e0) =====
__global__ __launch_bounds__(256) void proj_scatter(
    const float* __restrict__ X, const float* __restrict__ W,
    const float* __restrict__ b, const int* __restrict__ perm,
    ushort* __restrict__ out, int M) {
    __shared__ float xs[64][4];
    int tid = threadIdx.x;
    int bm = blockIdx.x * 64;
    if (tid < 64) {
        float4 a = make_float4(0.f, 0.f, 0.f, 0.f);
        if (bm + tid < M) a = *(const float4*)(X + (size_t)(bm + tid) * 4);
        xs[tid][0] = a.x; xs[tid][1] = a.y; xs[tid][2] = a.z; xs[tid][3] = a.w;
    }
    __syncthreads();
    int rb = tid >> 4, h0 = (tid & 15) * 8;
    float acc[4][8];
#pragma unroll
    for (int j = 0; j < 4; ++j)
#pragma unroll
        for (int c = 0; c < 8; ++c) acc[j][c] = b[h0 + c];
#pragma unroll
    for (int k = 0; k < 4; ++k) {
        float4 w0 = *(const float4*)(W + k * TH + h0);
        float4 w1 = *(const float4*)(W + k * TH + h0 + 4);
#pragma unroll
        for (int j = 0; j < 4; ++j) {
            float xv = xs[rb + 16 * j][k];
            acc[j][0] = fmaf(xv, w0.x, acc[j][0]); acc[j][1] = fmaf(xv, w0.y, acc[j][1]);
            acc[j][2] = fmaf(xv, w0.z, acc[j][2]); acc[j][3] = fmaf(xv, w0.w, acc[j][3]);
            acc[j][4] = fmaf(xv, w1.x, acc[j][4]); acc[j][5] = fmaf(xv, w1.y, acc[j][5]);
            acc[j][6] = fmaf(xv, w1.z, acc[j][6]); acc[j][7] = fmaf(xv, w1.w, acc[j][7]);
        }
    }
#pragma unroll
    for (int j = 0; j < 4; ++j) {
        int row = bm + rb + 16 * j;
        if (row >= M) continue;
        ushort o[8];
#pragma unroll
        for (int c = 0; c < 8; ++c) {
            bf16 v = __float2bfloat16(acc[j][c]);
            o[c] = *(ushort*)&v;
        }
        *(uint4*)(out + (size_t)perm[row] * TH + h0) = *(uint4*)o;
    }
}

// ================= CSR build =================
__global__ void count_deg(const int* __restrict__ ei_dst, int* __restrict__ deg, int En) {
    int e = blockIdx.x * 256 + threadIdx.x;
    if (e < En) atomicAdd(&deg[ei_dst[e]], 1);
}
__global__ void scan_block(const int* __restrict__ deg, int* __restrict__ rowptr,
                           int* __restrict__ bsum, int Nn) {
    __shared__ int sm[256];
    int tid = threadIdx.x;
    int gid = blockIdx.x * 256 + tid;
    int v = (gid < Nn) ? deg[gid] : 0;
    int x = v;
    sm[tid] = x; __syncthreads();
    for (int off = 1; off < 256; off <<= 1) {
        int t = (tid >= off) ? sm[tid - off] : 0;
        __syncthreads();
        x += t; sm[tid] = x;
        __syncthreads();
    }
    if (gid < Nn) rowptr[gid] = x - v;
    if (tid == 255) bsum[blockIdx.x] = x;
}
__global__ void scan_bsum(const int* __restrict__ bsum, int* __restrict__ bsumx, int nb) {
    __shared__ int sm[512];
    int tid = threadIdx.x;
    int v = (tid < nb) ? bsum[tid] : 0;
    int x = v;
    sm[tid] = x; __syncthreads();
    for (int off = 1; off < 512; off <<= 1) {
        int t = (tid >= off) ? sm[tid - off] : 0;
        __syncthreads();
        x += t; sm[tid] = x;
        __syncthreads();
    }
    if (tid < nb) bsumx[tid] = x - v;
}
__global__ void add_off(int* __restrict__ rowptr, const int* __restrict__ bsumx,
                        int Nn, int Etot) {
    int gid = blockIdx.x * 256 + threadIdx.x;
    if (gid < Nn) rowptr[gid] += bsumx[gid >> 8];
    if (gid == 0) rowptr[Nn] = Etot;
}
__global__ void fill_csr(const int* __restrict__ ei_src, const int* __restrict__ ei_dst,
                         const int* __restrict__ rowptr, int* __restrict__ cur,
                         int* __restrict__ srcp, int* __restrict__ epos, int En) {
    int e = blockIdx.x * 256 + threadIdx.x;
    if (e >= En) return;
    int d = ei_dst[e];
    int p = atomicAdd(&cur[d], 1);
    int slot = rowptr[d] + p;
    srcp[slot] = ei_src[e];
    epos[e] = slot;
}
__global__ void build_gptr(const int* __restrict__ batch, int* __restrict__ gptr,
                           int Nn, int Gn) {
    int n = blockIdx.x * 256 + threadIdx.x;
    if (n >= Nn) return;
    int bc = batch[n];
    int bp = (n == 0) ? -1 : batch[n - 1];
    for (int g = bp + 1; g <= bc; ++g) gptr[g] = n;
    if (n == Nn - 1) for (int g = bc + 1; g <= Gn; ++g) gptr[g] = Nn;
}

// ========== aggregation, 16 threads/node, 8 ch/thread, 2-way unroll ==========
__global__ __launch_bounds__(256) void aggregate_v8(
    const ushort* __restrict__ node, const ushort* __restrict__ ef,
    const int* __restrict__ srcp, const int* __restrict__ rowptr,
    const float* __restrict__ eps, int l, ushort* __restrict__ zb, int Nn) {
    int t = blockIdx.x * 256 + threadIdx.x;
    int n = t >> 4;
    if (n >= Nn) return;
    int c8 = (t & 15) * 8;
    float se = 1.f + eps[l];
    float acc[8];
    uint4 nv = *(const uint4*)(node + (size_t)n * TH + c8);
    unpack8(nv, acc);
#pragma unroll
    for (int j = 0; j < 8; ++j) acc[j] *= se;
    int s0 = rowptr[n], s1 = rowptr[n + 1];
    int i = s0;
    for (; i + 1 < s1; i += 2) {
        int sa = srcp[i], sb = srcp[i + 1];
        uint4 av0 = *(const uint4*)(node + (size_t)sa * TH + c8);
        uint4 bv0 = *(const uint4*)(ef + (size_t)i * TH + c8);
        uint4 av1 = *(const uint4*)(node + (size_t)sb * TH + c8);
        uint4 bv1 = *(const uint4*)(ef + (size_t)(i + 1) * TH + c8);
        float a0[8], b0[8], a1[8], b1[8];
        unpack8(av0, a0); unpack8(bv0, b0);
        unpack8(av1, a1); unpack8(bv1, b1);
#pragma unroll
        for (int j = 0; j < 8; ++j)
            acc[j] += fmaxf(a0[j] + b0[j], 0.f) + fmaxf(a1[j] + b1[j], 0.f);
    }
    if (i < s1) {
        int sa = srcp[i];
        uint4 av = *(const uint4*)(node + (size_t)sa * TH + c8);
        uint4 bv = *(const uint4*)(ef + (size_t)i * TH + c8);
        float af[8], bf[8];
        unpack8(av, af); unpack8(bv, bf);
#pragma unroll
        for (int j = 0; j < 8; ++j) acc[j] += fmaxf(af[j] + bf[j], 0.f);
    }
    ushort o[8];
#pragma unroll
    for (int j = 0; j < 8; ++j) {
        bf16 v = __float2bfloat16(acc[j]);
        o[j] = *(ushort*)&v;
    }
    *(uint4*)(zb + (size_t)n * TH + c8) = *(uint4*)o;
}

// ===== fused 2-layer MLP (R5/R7 form): one tile per block, single 32 KB LDS =====
__global__ __launch_bounds__(256, 2) void mlp2_fused(
    const ushort* __restrict__ A, const ushort* __restrict__ W1t,
    const float* __restrict__ b1, const ushort* __restrict__ W2t,
    const float* __restrict__ b2, ushort* __restrict__ C, int M)
{
    __shared__ ushort As[128 * 128];
    const int tid = threadIdx.x;
    const int bm = blockIdx.x * 128;
    const int lane = tid & 63, w = tid >> 6;
    const int lr = lane & 15, lq = lane >> 4;
    const int wm = (w & 1) * 64, wn = (w >> 1) * 64;
    short8 wf[4][4];
#pragma unroll
    for (int ni = 0; ni < 4; ++ni)
#pragma unroll
        for (int ks = 0; ks < 4; ++ks)
            wf[ni][ks] = *(const short8*)(W1t + (size_t)(wn + ni * 16 + lr) * 128 + ks * 32 + lq * 8);
    // async staging: wave w covers slots [w*512, w*512+512)
#pragma unroll
    for (int i = 0; i < 8; ++i) {
        int s = w * 512 + i * 64 + lane;
        int r = s >> 4;
        int c = (s & 15) ^ (r & 15);
        gload_lds16(A + (size_t)(bm + r) * 128 + c * 8, As + (w * 512 + i * 64) * 8);
    }
    __syncthreads();
    f32x4 acc[4][4] = {};
#pragma unroll
    for (int ks = 0; ks < 4; ++ks) {
        int cb = ks * 4 + lq;
        short8 af[4];
#pragma unroll
        for (int mi = 0; mi < 4; ++mi)
            af[mi] = *(const short8*)(&As[(wm + mi * 16 + lr) * 128 + ((cb ^ lr) * 8)]);
#pragma unroll
        for (int mi = 0; mi < 4; ++mi)
#pragma unroll
            for (int ni = 0; ni < 4; ++ni)
                acc[mi][ni] = __builtin_amdgcn_mfma_f32_16x16x32_bf16(af[mi], wf[ni][ks], acc[mi][ni], 0, 0, 0);
    }
    __syncthreads();   // all As reads complete before in-place T write
#pragma unroll
    for (int mi = 0; mi < 4; ++mi)
#pragma unroll
        for (int reg = 0; reg < 4; ++reg) {
            int row = wm + mi * 16 + lq * 4 + reg;
#pragma unroll
            for (int ni = 0; ni < 4; ++ni) {
                int col = wn + ni * 16 + lr;
                float v = fmaxf(acc[mi][ni][reg] + b1[col], 0.f);
                bf16 bv = __float2bfloat16(v);
                As[row * 128 + (((col >> 3) ^ (row & 15)) * 8) + (col & 7)] = *(ushort*)&bv;
            }
        }
    // preload W2 (independent of LDS; latency hides under barrier)
#pragma unroll
    for (int ni = 0; ni < 4; ++ni)
#pragma unroll
        for (int ks = 0; ks < 4; ++ks)
            wf[ni][ks] = *(const short8*)(W2t + (size_t)(wn + ni * 16 + lr) * 128 + ks * 32 + lq * 8);
    __syncthreads();
    {
        f32x4 acc2[4][4] = {};
#pragma unroll
        for (int ks = 0; ks < 4; ++ks) {
            int cb = ks * 4 + lq;
            short8 af[4];
#pragma unroll
            for (int mi = 0; mi < 4; ++mi)
                af[mi] = *(const short8*)(&As[(wm + mi * 16 + lr) * 128 + ((cb ^ lr) * 8)]);
#pragma unroll
            for (int mi = 0; mi < 4; ++mi)
#pragma unroll
                for (int ni = 0; ni < 4; ++ni)
                    acc2[mi][ni] = __builtin_amdgcn_mfma_f32_16x16x32_bf16(af[mi], wf[ni][ks], acc2[mi][ni], 0, 0, 0);
        }
#pragma unroll
        for (int mi = 0; mi < 4; ++mi)
#pragma unroll
            for (int reg = 0; reg < 4; ++reg) {
                int row = bm + wm + mi * 16 + lq * 4 + reg;
                if (row >= M) continue;
#pragma unroll
                for (int ni = 0; ni < 4; ++ni) {
                    int col = wn + ni * 16 + lr;
                    bf16 bv = __float2bfloat16(acc2[mi][ni][reg] + b2[col]);
                    C[(size_t)row * 128 + col] = *(ushort*)&bv;
                }
            }
    }
}

// ===== fused GRU v6 (R8 proven): weight-stationary, dbuf, counted vmcnt, grid 512 =====
__global__ __launch_bounds__(512, 2) void gru_fused(
    const ushort* __restrict__ mfeat, const ushort* __restrict__ wih,
    const ushort* __restrict__ whh, const float* __restrict__ bih,
    const float* __restrict__ bhh, ushort* __restrict__ node, int Nn, int nT)
{
    __shared__ ushort Ms[2][64 * 128];
    __shared__ ushort Hs[2][64 * 128];
    const int tid = threadIdx.x;
    const int lane = tid & 63, w = tid >> 6;
    const int lr = lane & 15, lq = lane >> 4;
    const int col = w * 16 + lr;
    short8 W[6][4];
#pragma unroll
    for (int ks = 0; ks < 4; ++ks) {
        int koff = ks * 32 + lq * 8;
        W[0][ks] = *(const short8*)(wih + (size_t)col * 128 + koff);
        W[1][ks] = *(const short8*)(wih + (size_t)(128 + col) * 128 + koff);
        W[2][ks] = *(const short8*)(wih + (size_t)(256 + col) * 128 + koff);
        W[3][ks] = *(const short8*)(whh + (size_t)col * 128 + koff);
        W[4][ks] = *(const short8*)(whh + (size_t)(128 + col) * 128 + koff);
        W[5][ks] = *(const short8*)(whh + (size_t)(256 + col) * 128 + koff);
    }
    const float br  = bih[col] + bhh[col];
    const float bz  = bih[128 + col] + bhh[128 + col];
    const float bin = bih[256 + col], bhn = bhh[256 + col];

    auto stage = [&](int tt, int buf) {
#pragma unroll
        for (int i = 0; i < 2; ++i) {
            int sb = w * 128 + i * 64;
            int s = sb + lane;
            int r = s >> 4;
            int c = (s & 15) ^ (r & 15);
            size_t goff = (size_t)(tt * 64 + r) * 128 + c * 8;
            gload_lds16(mfeat + goff, &Ms[buf][sb * 8]);
            gload_lds16(node + goff, &Hs[buf][sb * 8]);
        }
    };

    int t = blockIdx.x;
    const int G = gridDim.x;
    if (t >= nT) return;
    stage(t, 0);
    int cur = 0;
    while (t < nT) {
        int tn = t + G;
        if (tn < nT) {
            stage(tn, cur ^ 1);
            asm volatile("s_waitcnt vmcnt(4)" ::: "memory");
        } else {
            asm volatile("s_waitcnt vmcnt(0)" ::: "memory");
        }
        __builtin_amdgcn_sched_barrier(0);
        __builtin_amdgcn_s_barrier();
        __builtin_amdgcn_sched_barrier(0);
        {
            const ushort* Mc = Ms[cur];
            const ushort* Hc = Hs[cur];
            f32x4 aR[4] = {}, aZ[4] = {}, aN[4] = {}, aH[4] = {};
#pragma unroll
            for (int ks = 0; ks < 4; ++ks) {
                int cb = ks * 4 + lq;
#pragma unroll
                for (int rt = 0; rt < 4; ++rt) {
                    int off = (rt * 16 + lr) * 128 + ((cb ^ lr) * 8);
                    short8 am = *(const short8*)(&Mc[off]);
                    short8 ah = *(const short8*)(&Hc[off]);
                    aR[rt] = __builtin_amdgcn_mfma_f32_16x16x32_bf16(am, W[0][ks], aR[rt], 0, 0, 0);
                    aR[rt] = __builtin_amdgcn_mfma_f32_16x16x32_bf16(ah, W[3][ks], aR[rt], 0, 0, 0);
                    aZ[rt] = __builtin_amdgcn_mfma_f32_16x16x32_bf16(am, W[1][ks], aZ[rt], 0, 0, 0);
                    aZ[rt] = __builtin_amdgcn_mfma_f32_16x16x32_bf16(ah, W[4][ks], aZ[rt], 0, 0, 0);
                    aN[rt] = __builtin_amdgcn_mfma_f32_16x16x32_bf16(am, W[2][ks], aN[rt], 0, 0, 0);
                    aH[rt] = __builtin_amdgcn_mfma_f32_16x16x32_bf16(ah, W[5][ks], aH[rt], 0, 0, 0);
                }
            }
            const int bm = t * 64;
#pragma unroll
            for (int rt = 0; rt < 4; ++rt)
#pragma unroll
                for (int reg = 0; reg < 4; ++reg) {
                    int lrow = rt * 16 + lq * 4 + reg;
                    int row = bm + lrow;
                    if (row >= Nn) continue;
                    float r = sigm(aR[rt][reg] + br);
                    float z = sigm(aZ[rt][reg] + bz);
                    float n = ftanh(aN[rt][reg] + bin + r * (aH[rt][reg] + bhn));
                    int hofs = lrow * 128 + (((col >> 3) ^ (lrow & 15)) * 8) + (col & 7);
                    float hold = __bfloat162float(*(const bf16*)&Hc[hofs]);
                    bf16 hv = __float2bfloat16((1.f - z) * n + z * hold);
                    node[(size_t)row * 128 + col] = *(ushort*)&hv;
                }
        }
        __builtin_amdgcn_sched_barrier(0);
        __builtin_amdgcn_s_barrier();
        __builtin_amdgcn_sched_barrier(0);
        cur ^= 1;
        t = tn;
    }
}

// ================= fused LSTM step (16 graphs/block) =================
__global__ __launch_bounds__(256) void lstm_fused(
    ushort* __restrict__ s, const ushort* __restrict__ Wl,
    const float* __restrict__ bih, const float* __restrict__ bhh,
    float* __restrict__ cl, int Gn)
{
    __shared__ ushort Ss[16 * 256];
    const int tid = threadIdx.x;
    const int bm = blockIdx.x * 16;
#pragma unroll
    for (int p = 0; p < 2; ++p) {
        int ch = p * 256 + tid;
        int r = ch >> 5, c = ch & 31;
        int row = bm + r;
        uint4 v = make_uint4(0u, 0u, 0u, 0u);
        if (row < Gn) v = *(const uint4*)(s + (size_t)row * 256 + c * 8);
        *(uint4*)(&Ss[r * 256 + ((c ^ (r & 15)) * 8)]) = v;
    }
    __syncthreads();
    const int lane = tid & 63, w = tid >> 6;
    const int lr = lane & 15, lq = lane >> 4;
    f32x4 acc[4][2] = {};
#pragma unroll
    for (int ks = 0; ks < 8; ++ks) {
        int cb = ks * 4 + lq;
        short8 am = *(const short8*)(&Ss[lr * 256 + ((cb ^ lr) * 8)]);
        int koff = ks * 32 + lq * 8;
#pragma unroll
        for (int g = 0; g < 4; ++g)
#pragma unroll
            for (int sub = 0; sub < 2; ++sub) {
                int col = g * 128 + w * 32 + sub * 16 + lr;
                short8 bf = *(const short8*)(Wl + (size_t)col * 256 + koff);
                acc[g][sub] = __builtin_amdgcn_mfma_f32_16x16x32_bf16(am, bf, acc[g][sub], 0, 0, 0);
            }
    }
#pragma unroll
    for (int sub = 0; sub < 2; ++sub) {
        int h = w * 32 + sub * 16 + lr;
        float bi = bih[h] + bhh[h];
        float bff = bih[128 + h] + bhh[128 + h];
        float bg = bih[256 + h] + bhh[256 + h];
        float bo = bih[384 + h] + bhh[384 + h];
#pragma unroll
        for (int reg = 0; reg < 4; ++reg) {
            int row = bm + lq * 4 + reg;
            if (row >= Gn) continue;
            float iv = sigm(acc[0][sub][reg] + bi);
            float fv = sigm(acc[1][sub][reg] + bff);
            float gv = ftanh(acc[2][sub][reg] + bg);
            float ov = sigm(acc[3][sub][reg] + bo);
            float c = fv * cl[(size_t)row * 128 + h] + iv * gv;
            cl[(size_t)row * 128 + h] = c;
            bf16 hv = __float2bfloat16(ov * ftanh(c));
            s[(size_t)row * 256 + h] = *(ushort*)&hv;
        }
    }
}

// ================= fused per-graph attention (vectorized, no reg cache) =========
__global__ __launch_bounds__(256) void att_fused(
    const ushort* __restrict__ node, ushort* __restrict__ s,
    const int* __restrict__ gptr)
{
    __shared__ float q[128];
    __shared__ float es[512];
    __shared__ float red[8];
    __shared__ float part[16][128];
    int g = blockIdx.x;
    int tid = threadIdx.x, lane = tid & 63, wid = tid >> 6;
    int n0 = gptr[g], n1 = gptr[g + 1];
    int cnt = n1 - n0; if (cnt > 512) cnt = 512;
    if (tid < 128) q[tid] = __bfloat162float(((const bf16*)s)[(size_t)g * 256 + tid]);
    __syncthreads();
    int gr = tid >> 4, c8 = (tid & 15) * 8;
    for (int i0 = 0; i0 < cnt; i0 += 16) {
        int i = i0 + gr;
        float p = 0.f;
        if (i < cnt) {
            uint4 v = *(const uint4*)(node + (size_t)(n0 + i) * TH + c8);
            float f[8]; unpack8(v, f);
#pragma unroll
            for (int j = 0; j < 8; ++j) p = fmaf(f[j], q[c8 + j], p);
        }
        p += __shfl_down(p, 8, 16);
        p += __shfl_down(p, 4, 16);
        p += __shfl_down(p, 2, 16);
        p += __shfl_down(p, 1, 16);
        if ((tid & 15) == 0 && i < cnt) es[i] = p;
    }
    __syncthreads();
    float m = -1e30f;
    for (int i = tid; i < cnt; i += 256) m = fmaxf(m, es[i]);
    for (int off = 32; off; off >>= 1) m = fmaxf(m, __shfl_down(m, off));
    if (lane == 0) red[wid] = m;
    __syncthreads();
    m = fmaxf(fmaxf(red[0], red[1]), fmaxf(red[2], red[3]));
    float sm = 0.f;
    for (int i = tid; i < cnt; i += 256) { float ex = __expf(es[i] - m); es[i] = ex; sm += ex; }
    for (int off = 32; off; off >>= 1) sm += __shfl_down(sm, off);
    if (lane == 0) red[4 + wid] = sm;
    __syncthreads();
    sm = red[4] + red[5] + red[6] + red[7];
    float inv = 1.f / fmaxf(sm, 1e-9f);
    float racc[8] = {};
    for (int i = gr; i < cnt; i += 16) {
        uint4 v = *(const uint4*)(node + (size_t)(n0 + i) * TH + c8);
        float f[8]; unpack8(v, f);
        float a = es[i];
#pragma unroll
        for (int j = 0; j < 8; ++j) racc[j] = fmaf(a, f[j], racc[j]);
    }
#pragma unroll
    for (int j = 0; j < 8; ++j) part[gr][c8 + j] = racc[j];
    __syncthreads();
    if (tid < 128) {
        float r = 0.f;
#pragma unroll
        for (int k = 0; k < 16; ++k) r += part[k][tid];
        bf16 rv = __float2bfloat16(r * inv);
        s[(size_t)g * 256 + 128 + tid] = *(ushort*)&rv;
    }
}

// ===== final FC, 16 graphs/block: w1 loaded once per 16 graphs (16x less L2) =====
// Threads: (h = tid&127, half = tid>>7) stream w1 rows once, FMA into 16
// per-graph accs (static idx); halves combined in LDS; 16-lane group reduce.
__global__ __launch_bounds__(256) void final_fc16(
    const ushort* __restrict__ s,
    const float* __restrict__ w1, const float* __restrict__ b1,
    const float* __restrict__ w2, const float* __restrict__ b2,
    float* __restrict__ out, int Gn)
{
    __shared__ float qsL[16][264];
    __shared__ float hsum[2][16][136];
    const int tid = threadIdx.x;
    const int g0 = blockIdx.x * 16;
    // stage 16 graphs x 256 ch (bf16 -> f32), coalesced
#pragma unroll
    for (int p = 0; p < 2; ++p) {
        int slot = p * 256 + tid;          // 0..511
        int g = slot >> 5, c = slot & 31;
        int row = g0 + g;
        uint4 v = make_uint4(0u, 0u, 0u, 0u);
        if (row < Gn) v = *(const uint4*)(s + (size_t)row * 256 + c * 8);
        float f[8]; unpack8(v, f);
#pragma unroll
        for (int j = 0; j < 8; ++j) qsL[g][c * 8 + j] = f[j];
    }
    __syncthreads();
    const int h = tid & 127, half = tid >> 7;
    float acc[16];
#pragma unroll
    for (int g = 0; g < 16; ++g) acc[g] = 0.f;
    const int k0 = half * 128;
    for (int k = 0; k < 128; ++k) {
        float wv = w1[(size_t)(k0 + k) * 128 + h];
#pragma unroll
        for (int g = 0; g < 16; ++g) acc[g] = fmaf(qsL[g][k0 + k], wv, acc[g]);
    }
#pragma unroll
    for (int g = 0; g < 16; ++g) hsum[half][g][h] = acc[g];
    __syncthreads();
    const int gi = tid >> 4, l16 = tid & 15;
    float p = 0.f;
    for (int hh = l16; hh < 128; hh += 16) {
        float v = hsum[0][gi][hh] + hsum[1][gi][hh] + b1[hh];
        p = fmaf(fmaxf(v, 0.f), w2[hh], p);
    }
#pragma unroll
    for (int off = 8; off; off >>= 1) p += __shfl_xor(p, off, 16);
    if (l16 == 0 && g0 + gi < Gn) out[g0 + gi] = p + b2[0];
}

// ---------------------------------------------------------------------------
static void launch_mlp2(const void* A, const bf16* W1t, const float* b1,
                        const bf16* W2t, const float* b2, void* C, int M, hipStream_t s) {
    hipLaunchKernelGGL(mlp2_fused, dim3((M + 127) / 128), dim3(256), 0, s,
                       (const ushort*)A, (const ushort*)W1t, b1, (const ushort*)W2t, b2,
                       (ushort*)C, M);
}

extern "C" void kernel_launch(void* const* d_in, const int* in_sizes, int n_in,
                              void* d_out, int out_size, void* d_ws, size_t ws_size,
                              hipStream_t stream) {
    const float* x         = (const float*)d_in[0];
    const float* edge_attr = (const float*)d_in[1];
    const int*   edge_index= (const int*)d_in[2];
    const int*   batch     = (const int*)d_in[3];
    const float* node_w    = (const float*)d_in[4];
    const float* node_b    = (const float*)d_in[5];
    const float* edge_w    = (const float*)d_in[6];
    const float* edge_b    = (const float*)d_in[7];
    const float* eps       = (const float*)d_in[8];
    const float* gin_w1    = (const float*)d_in[9];
    const float* gin_b1    = (const float*)d_in[10];
    const float* gin_w2    = (const float*)d_in[11];
    const float* gin_b2    = (const float*)d_in[12];
    const float* em_w1     = (const float*)d_in[13];
    const float* em_b1     = (const float*)d_in[14];
    const float* em_w2     = (const float*)d_in[15];
    const float* em_b2     = (const float*)d_in[16];
    const float* gru_wih   = (const float*)d_in[17];
    const float* gru_whh   = (const float*)d_in[18];
    const float* gru_bih   = (const float*)d_in[19];
    const float* gru_bhh   = (const float*)d_in[20];
    const float* lstm_wih  = (const float*)d_in[21];
    const float* lstm_whh  = (const float*)d_in[22];
    const float* lstm_bih  = (const float*)d_in[23];
    const float* lstm_bhh  = (const float*)d_in[24];
    const float* fc_w1     = (const float*)d_in[25];
    const float* fc_b1     = (const float*)d_in[26];
    const float* fc_w2     = (const float*)d_in[27];
    const float* fc_b2     = (const float*)d_in[28];
    float* out = (float*)d_out;
    const int* ei_src = edge_index;
    const int* ei_dst = edge_index + TE;

    // ---- workspace layout ----
    char* base = (char*)d_ws;
    size_t off = 0;
    auto alloc = [&](size_t bytes) { void* p = base + off; off += (bytes + 15) & ~size_t(15); return p; };
    bf16*  nodeb = (bf16*)alloc((size_t)TN * TH * 2);   // 25.6 MB
    bf16*  zb    = (bf16*)alloc((size_t)TN * TH * 2);   // 25.6 MB
    bf16*  e1b   = (bf16*)alloc((size_t)TE * TH * 2);   // 51.2 MB (set2set overlay later)
    int*   deg   = (int*)alloc((size_t)TN * 4);
    int*   rowptr= (int*)alloc((size_t)(TN + 1) * 4);
    int*   cur   = (int*)alloc((size_t)TN * 4);
    int*   srcp  = (int*)alloc((size_t)TE * 4);
    int*   epos  = (int*)alloc((size_t)TE * 4);
    int*   bsum  = (int*)alloc(512 * 4);
    int*   bsumx = (int*)alloc(512 * 4);
    int*   gptr  = (int*)alloc((size_t)(TG + 1) * 4);
    bf16*  w6    = (bf16*)alloc(6 * TH * TH * 2);
    bf16*  wgru  = (bf16*)alloc(2 * 384 * TH * 2);
    bf16*  wl    = (bf16*)alloc(512 * 256 * 2);
    if (ws_size < off) return;

    bf16* w_gin1_0 = w6;
    bf16* w_gin1_1 = w6 + 1 * TH * TH;
    bf16* w_gin2_0 = w6 + 2 * TH * TH;
    bf16* w_gin2_1 = w6 + 3 * TH * TH;
    bf16* w_em1    = w6 + 4 * TH * TH;
    bf16* w_em2    = w6 + 5 * TH * TH;
    bf16* w_wih    = wgru;
    bf16* w_whh    = wgru + 384 * TH;

    ushort* sbuf = (ushort*)e1b;                      // [G][256] bf16
    float*  cl   = (float*)(sbuf + (size_t)TG * 256); // [G][128] fp32

    // ---- CSR + gptr ----
    hipMemsetAsync(deg, 0, (size_t)TN * 4, stream);
    hipMemsetAsync(cur, 0, (size_t)TN * 4, stream);
    count_deg<<<(TE + 255) / 256, 256, 0, stream>>>(ei_dst, deg, TE);
    int nb = (TN + 255) / 256;
    scan_block<<<nb, 256, 0, stream>>>(deg, rowptr, bsum, TN);
    scan_bsum<<<1, 512, 0, stream>>>(bsum, bsumx, nb);
    add_off<<<nb, 256, 0, stream>>>(rowptr, bsumx, TN, TE);
    fill_csr<<<(TE + 255) / 256, 256, 0, stream>>>(ei_src, ei_dst, rowptr, cur, srcp, epos, TE);
    build_gptr<<<(TN + 255) / 256, 256, 0, stream>>>(batch, gptr, TN, TG);

    // ---- weights (one merged kernel) ----
    int convTot = 6 * TH * TH + 2 * 384 * TH + 512 * 256;
    convAll<<<(convTot + 255) / 256, 256, 0, stream>>>(
        gin_w1, gin_w2, em_w1, em_w2, gru_wih, gru_whh, lstm_wih, lstm_whh,
        w6, wgru, wl);

    // ---- projections (edges scattered into CSR slot order) ----
    proj64<14><<<(TN + 63) / 64, 256, 0, stream>>>(x, node_w, node_b, (ushort*)nodeb, TN);
    proj_scatter<<<(TE + 63) / 64, 256, 0, stream>>>(edge_attr, edge_w, edge_b,
                                                     epos, (ushort*)e1b, TE);

    const int ntG = (TN + 63) / 64;   // gru tiles

    // ---- layer 0: aggregate -> zb; MLP in-place; GRU ----
    aggregate_v8<<<(TN * 16 + 255) / 256, 256, 0, stream>>>(
        (const ushort*)nodeb, (const ushort*)e1b, srcp, rowptr, eps, 0, (ushort*)zb, TN);
    launch_mlp2(zb, w_gin1_0, gin_b1, w_gin2_0, gin_b2, zb, TN, stream);
    gru_fused<<<512, 512, 0, stream>>>(
        (const ushort*)zb, (const ushort*)w_wih, (const ushort*)w_whh,
        gru_bih, gru_bhh, (ushort*)nodeb, TN, ntG);

    // ---- edge MLP in-place (slot order preserved), layer 1 ----
    launch_mlp2(e1b, w_em1, em_b1, w_em2, em_b2, e1b, TE, stream);
    aggregate_v8<<<(TN * 16 + 255) / 256, 256, 0, stream>>>(
        (const ushort*)nodeb, (const ushort*)e1b, srcp, rowptr, eps, 1, (ushort*)zb, TN);
    launch_mlp2(zb, w_gin1_1, gin_b1 + TH, w_gin2_1, gin_b2 + TH, zb, TN, stream);
    gru_fused<<<512, 512, 0, stream>>>(
        (const ushort*)zb, (const ushort*)w_wih, (const ushort*)w_whh,
        gru_bih, gru_bhh, (ushort*)nodeb, TN, ntG);

    // ---- Set2Set (3 steps) ----
    hipMemsetAsync(sbuf, 0, (size_t)TG * 256 * 2 + (size_t)TG * 128 * 4, stream);
    for (int st = 0; st < 3; ++st) {
        lstm_fused<<<(TG + 15) / 16, 256, 0, stream>>>(
            sbuf, (const ushort*)wl, lstm_bih, lstm_bhh, cl, TG);
        att_fused<<<TG, 256, 0, stream>>>((const ushort*)nodeb, sbuf, gptr);
    }

    // ---- final FC (16 graphs/block) ----
    final_fc16<<<(TG + 15) / 16, 256, 0, stream>>>(
        sbuf, fc_w1, fc_b1, fc_w2, fc_b2, out, TG);
}

// Round 13
// 512.381 us; speedup vs baseline: 1.0882x; 1.0080x over previous
//
#include <hip/hip_runtime.h>
#include <hip/hip_bf16.h>

constexpr int TN = 100000;   // nodes
constexpr int TE = 200000;   // edges
constexpr int TG = 4000;     // graphs
constexpr int TH = 128;      // hidden

using short8 = __attribute__((ext_vector_type(8))) short;
using f32x4  = __attribute__((ext_vector_type(4))) float;
typedef __hip_bfloat16 bf16;

#define DEVINL __device__ __forceinline__
DEVINL float sigm(float x)  { return 1.f / (1.f + __expf(-x)); }
DEVINL float ftanh(float x) { return 1.f - 2.f / (__expf(2.f * x) + 1.f); }
DEVINL void unpack8(uint4 v, float* f) {
    const ushort* u = (const ushort*)&v;
#pragma unroll
    for (int j = 0; j < 8; ++j) f[j] = __bfloat162float(*(const bf16*)&u[j]);
}

// async global->LDS, 16B per lane; dest = uniform base + lane*16
DEVINL void gload_lds16(const ushort* gsrc, ushort* ldst) {
    __builtin_amdgcn_global_load_lds(
        (const __attribute__((address_space(1))) void*)gsrc,
        (__attribute__((address_space(3))) void*)ldst, 16, 0, 0);
}

// ================= merged weight conversion =================
__global__ void convAll(const float* __restrict__ g1, const float* __restrict__ g2,
                        const float* __restrict__ e1, const float* __restrict__ e2,
                        const float* __restrict__ gwih, const float* __restrict__ gwhh,
                        const float* __restrict__ lwih, const float* __restrict__ lwhh,
                        bf16* __restrict__ w6, bf16* __restrict__ wgru,
                        bf16* __restrict__ wl) {
    int i = blockIdx.x * 256 + threadIdx.x;
    if (i < 6 * TH * TH) {
        int m = i >> 14, r = i & 16383;
        int n = r >> 7, k = r & 127;
        const float* s = (m == 0) ? g1 : (m == 1) ? g1 + TH * TH
                       : (m == 2) ? g2 : (m == 3) ? g2 + TH * TH
                       : (m == 4) ? e1 : e2;
        w6[i] = __float2bfloat16(s[k * TH + n]);
        return;
    }
    i -= 6 * TH * TH;
    if (i < 2 * 384 * TH) {
        const float* s = (i < 384 * TH) ? gwih : gwhh;
        int r = (i < 384 * TH) ? i : i - 384 * TH;
        wgru[i] = __float2bfloat16(s[r]);
        return;
    }
    i -= 2 * 384 * TH;
    if (i < 512 * 256) {
        int c = i >> 8, k = i & 255;
        float v = (k < 128) ? lwih[c * 256 + k] + lwhh[c * 128 + k] : lwih[c * 256 + k];
        wl[i] = __float2bfloat16(v);
    }
}

// ================= node projection: 64 rows/block ============
template<int K>
__global__ __launch_bounds__(256) void proj64(const float* __restrict__ X,
                                              const float* __restrict__ W,
                                              const float* __restrict__ b,
                                              ushort* __restrict__ out, int M) {
    __shared__ float xs[64][K];
    int tid = threadIdx.x;
    int bm = blockIdx.x * 64;
    for (int i = tid; i < 64 * K; i += 256) {
        int r = i / K, k = i % K;
        xs[r][k] = (bm + r < M) ? X[(size_t)(bm + r) * K + k] : 0.f;
    }
    __syncthreads();
    int rb = tid >> 4, h0 = (tid & 15) * 8;
    float acc[4][8];
#pragma unroll
    for (int j = 0; j < 4; ++j)
#pragma unroll
        for (int c = 0; c < 8; ++c) acc[j][c] = b[h0 + c];
#pragma unroll
    for (int k = 0; k < K; ++k) {
        float4 w0 = *(const float4*)(W + k * TH + h0);
        float4 w1 = *(const float4*)(W + k * TH + h0 + 4);
#pragma unroll
        for (int j = 0; j < 4; ++j) {
            float xv = xs[rb + 16 * j][k];
            acc[j][0] = fmaf(xv, w0.x, acc[j][0]); acc[j][1] = fmaf(xv, w0.y, acc[j][1]);
            acc[j][2] = fmaf(xv, w0.z, acc[j][2]); acc[j][3] = fmaf(xv, w0.w, acc[j][3]);
            acc[j][4] = fmaf(xv, w1.x, acc[j][4]); acc[j][5] = fmaf(xv, w1.y, acc[j][5]);
            acc[j][6] = fmaf(xv, w1.z, acc[j][6]); acc[j][7] = fmaf(xv, w1.w, acc[j][7]);
        }
    }
#pragma unroll
    for (int j = 0; j < 4; ++j) {
        int row = bm + rb + 16 * j;
        if (row >= M) continue;
        ushort o[8];
#pragma unroll
        for (int c = 0; c < 8; ++c) {
            bf16 v = __float2bfloat16(acc[j][c]);
            o[c] = *(ushort*)&v;
        }
        *(uint4*)(out + (size_t)row * TH + h0) = *(uint4*)o;
    }
}

// ===== proj_scatter: K=4 projection with CSR-slot scatter (layer-0 e0) =====
__global__ __launch_bounds__(256) void proj_scatter(
    const float* __restrict__ X, const float* __restrict__ W,
    const float* __restrict__ b, const int* __restrict__ perm,
    ushort* __restrict__ out, int M) {
    __shared__ float xs[64][4];
    int tid = threadIdx.x;
    int bm = blockIdx.x * 64;
    if (tid < 64) {
        float4 a = make_float4(0.f, 0.f, 0.f, 0.f);
        if (bm + tid < M) a = *(const float4*)(X + (size_t)(bm + tid) * 4);
        xs[tid][0] = a.x; xs[tid][1] = a.y; xs[tid][2] = a.z; xs[tid][3] = a.w;
    }
    __syncthreads();
    int rb = tid >> 4, h0 = (tid & 15) * 8;
    float acc[4][8];
#pragma unroll
    for (int j = 0; j < 4; ++j)
#pragma unroll
        for (int c = 0; c < 8; ++c) acc[j][c] = b[h0 + c];
#pragma unroll
    for (int k = 0; k < 4; ++k) {
        float4 w0 = *(const float4*)(W + k * TH + h0);
        float4 w1 = *(const float4*)(W + k * TH + h0 + 4);
#pragma unroll
        for (int j = 0; j < 4; ++j) {
            float xv = xs[rb + 16 * j][k];
            acc[j][0] = fmaf(xv, w0.x, acc[j][0]); acc[j][1] = fmaf(xv, w0.y, acc[j][1]);
            acc[j][2] = fmaf(xv, w0.z, acc[j][2]); acc[j][3] = fmaf(xv, w0.w, acc[j][3]);
            acc[j][4] = fmaf(xv, w1.x, acc[j][4]); acc[j][5] = fmaf(xv, w1.y, acc[j][5]);
            acc[j][6] = fmaf(xv, w1.z, acc[j][6]); acc[j][7] = fmaf(xv, w1.w, acc[j][7]);
        }
    }
#pragma unroll
    for (int j = 0; j < 4; ++j) {
        int row = bm + rb + 16 * j;
        if (row >= M) continue;
        ushort o[8];
#pragma unroll
        for (int c = 0; c < 8; ++c) {
            bf16 v = __float2bfloat16(acc[j][c]);
            o[c] = *(ushort*)&v;
        }
        *(uint4*)(out + (size_t)perm[row] * TH + h0) = *(uint4*)o;
    }
}

// ================= CSR build =================
__global__ void count_deg(const int* __restrict__ ei_dst, int* __restrict__ deg, int En) {
    int e = blockIdx.x * 256 + threadIdx.x;
    if (e < En) atomicAdd(&deg[ei_dst[e]], 1);
}
__global__ void scan_block(const int* __restrict__ deg, int* __restrict__ rowptr,
                           int* __restrict__ bsum, int Nn) {
    __shared__ int sm[256];
    int tid = threadIdx.x;
    int gid = blockIdx.x * 256 + tid;
    int v = (gid < Nn) ? deg[gid] : 0;
    int x = v;
    sm[tid] = x; __syncthreads();
    for (int off = 1; off < 256; off <<= 1) {
        int t = (tid >= off) ? sm[tid - off] : 0;
        __syncthreads();
        x += t; sm[tid] = x;
        __syncthreads();
    }
    if (gid < Nn) rowptr[gid] = x - v;
    if (tid == 255) bsum[blockIdx.x] = x;
}
__global__ void scan_bsum(const int* __restrict__ bsum, int* __restrict__ bsumx, int nb) {
    __shared__ int sm[512];
    int tid = threadIdx.x;
    int v = (tid < nb) ? bsum[tid] : 0;
    int x = v;
    sm[tid] = x; __syncthreads();
    for (int off = 1; off < 512; off <<= 1) {
        int t = (tid >= off) ? sm[tid - off] : 0;
        __syncthreads();
        x += t; sm[tid] = x;
        __syncthreads();
    }
    if (tid < nb) bsumx[tid] = x - v;
}
__global__ void add_off(int* __restrict__ rowptr, const int* __restrict__ bsumx,
                        int Nn, int Etot) {
    int gid = blockIdx.x * 256 + threadIdx.x;
    if (gid < Nn) rowptr[gid] += bsumx[gid >> 8];
    if (gid == 0) rowptr[Nn] = Etot;
}
__global__ void fill_csr(const int* __restrict__ ei_src, const int* __restrict__ ei_dst,
                         const int* __restrict__ rowptr, int* __restrict__ cur,
                         int* __restrict__ srcp, int* __restrict__ epos, int En) {
    int e = blockIdx.x * 256 + threadIdx.x;
    if (e >= En) return;
    int d = ei_dst[e];
    int p = atomicAdd(&cur[d], 1);
    int slot = rowptr[d] + p;
    srcp[slot] = ei_src[e];
    epos[e] = slot;
}
__global__ void build_gptr(const int* __restrict__ batch, int* __restrict__ gptr,
                           int Nn, int Gn) {
    int n = blockIdx.x * 256 + threadIdx.x;
    if (n >= Nn) return;
    int bc = batch[n];
    int bp = (n == 0) ? -1 : batch[n - 1];
    for (int g = bp + 1; g <= bc; ++g) gptr[g] = n;
    if (n == Nn - 1) for (int g = bc + 1; g <= Gn; ++g) gptr[g] = Nn;
}

// ========== aggregation, 16 threads/node, 8 ch/thread, 2-way unroll ==========
__global__ __launch_bounds__(256) void aggregate_v8(
    const ushort* __restrict__ node, const ushort* __restrict__ ef,
    const int* __restrict__ srcp, const int* __restrict__ rowptr,
    const float* __restrict__ eps, int l, ushort* __restrict__ zb, int Nn) {
    int t = blockIdx.x * 256 + threadIdx.x;
    int n = t >> 4;
    if (n >= Nn) return;
    int c8 = (t & 15) * 8;
    float se = 1.f + eps[l];
    float acc[8];
    uint4 nv = *(const uint4*)(node + (size_t)n * TH + c8);
    unpack8(nv, acc);
#pragma unroll
    for (int j = 0; j < 8; ++j) acc[j] *= se;
    int s0 = rowptr[n], s1 = rowptr[n + 1];
    int i = s0;
    for (; i + 1 < s1; i += 2) {
        int sa = srcp[i], sb = srcp[i + 1];
        uint4 av0 = *(const uint4*)(node + (size_t)sa * TH + c8);
        uint4 bv0 = *(const uint4*)(ef + (size_t)i * TH + c8);
        uint4 av1 = *(const uint4*)(node + (size_t)sb * TH + c8);
        uint4 bv1 = *(const uint4*)(ef + (size_t)(i + 1) * TH + c8);
        float a0[8], b0[8], a1[8], b1[8];
        unpack8(av0, a0); unpack8(bv0, b0);
        unpack8(av1, a1); unpack8(bv1, b1);
#pragma unroll
        for (int j = 0; j < 8; ++j)
            acc[j] += fmaxf(a0[j] + b0[j], 0.f) + fmaxf(a1[j] + b1[j], 0.f);
    }
    if (i < s1) {
        int sa = srcp[i];
        uint4 av = *(const uint4*)(node + (size_t)sa * TH + c8);
        uint4 bv = *(const uint4*)(ef + (size_t)i * TH + c8);
        float af[8], bf[8];
        unpack8(av, af); unpack8(bv, bf);
#pragma unroll
        for (int j = 0; j < 8; ++j) acc[j] += fmaxf(af[j] + bf[j], 0.f);
    }
    ushort o[8];
#pragma unroll
    for (int j = 0; j < 8; ++j) {
        bf16 v = __float2bfloat16(acc[j]);
        o[j] = *(ushort*)&v;
    }
    *(uint4*)(zb + (size_t)n * TH + c8) = *(uint4*)o;
}

// ===== fused 2-layer MLP (R5/R7 form): one tile per block, single 32 KB LDS =====
__global__ __launch_bounds__(256, 2) void mlp2_fused(
    const ushort* __restrict__ A, const ushort* __restrict__ W1t,
    const float* __restrict__ b1, const ushort* __restrict__ W2t,
    const float* __restrict__ b2, ushort* __restrict__ C, int M)
{
    __shared__ ushort As[128 * 128];
    const int tid = threadIdx.x;
    const int bm = blockIdx.x * 128;
    const int lane = tid & 63, w = tid >> 6;
    const int lr = lane & 15, lq = lane >> 4;
    const int wm = (w & 1) * 64, wn = (w >> 1) * 64;
    short8 wf[4][4];
#pragma unroll
    for (int ni = 0; ni < 4; ++ni)
#pragma unroll
        for (int ks = 0; ks < 4; ++ks)
            wf[ni][ks] = *(const short8*)(W1t + (size_t)(wn + ni * 16 + lr) * 128 + ks * 32 + lq * 8);
    // async staging: wave w covers slots [w*512, w*512+512)
#pragma unroll
    for (int i = 0; i < 8; ++i) {
        int s = w * 512 + i * 64 + lane;
        int r = s >> 4;
        int c = (s & 15) ^ (r & 15);
        gload_lds16(A + (size_t)(bm + r) * 128 + c * 8, As + (w * 512 + i * 64) * 8);
    }
    __syncthreads();
    f32x4 acc[4][4] = {};
#pragma unroll
    for (int ks = 0; ks < 4; ++ks) {
        int cb = ks * 4 + lq;
        short8 af[4];
#pragma unroll
        for (int mi = 0; mi < 4; ++mi)
            af[mi] = *(const short8*)(&As[(wm + mi * 16 + lr) * 128 + ((cb ^ lr) * 8)]);
#pragma unroll
        for (int mi = 0; mi < 4; ++mi)
#pragma unroll
            for (int ni = 0; ni < 4; ++ni)
                acc[mi][ni] = __builtin_amdgcn_mfma_f32_16x16x32_bf16(af[mi], wf[ni][ks], acc[mi][ni], 0, 0, 0);
    }
    __syncthreads();   // all As reads complete before in-place T write
#pragma unroll
    for (int mi = 0; mi < 4; ++mi)
#pragma unroll
        for (int reg = 0; reg < 4; ++reg) {
            int row = wm + mi * 16 + lq * 4 + reg;
#pragma unroll
            for (int ni = 0; ni < 4; ++ni) {
                int col = wn + ni * 16 + lr;
                float v = fmaxf(acc[mi][ni][reg] + b1[col], 0.f);
                bf16 bv = __float2bfloat16(v);
                As[row * 128 + (((col >> 3) ^ (row & 15)) * 8) + (col & 7)] = *(ushort*)&bv;
            }
        }
    // preload W2 (independent of LDS; latency hides under barrier)
#pragma unroll
    for (int ni = 0; ni < 4; ++ni)
#pragma unroll
        for (int ks = 0; ks < 4; ++ks)
            wf[ni][ks] = *(const short8*)(W2t + (size_t)(wn + ni * 16 + lr) * 128 + ks * 32 + lq * 8);
    __syncthreads();
    {
        f32x4 acc2[4][4] = {};
#pragma unroll
        for (int ks = 0; ks < 4; ++ks) {
            int cb = ks * 4 + lq;
            short8 af[4];
#pragma unroll
            for (int mi = 0; mi < 4; ++mi)
                af[mi] = *(const short8*)(&As[(wm + mi * 16 + lr) * 128 + ((cb ^ lr) * 8)]);
#pragma unroll
            for (int mi = 0; mi < 4; ++mi)
#pragma unroll
                for (int ni = 0; ni < 4; ++ni)
                    acc2[mi][ni] = __builtin_amdgcn_mfma_f32_16x16x32_bf16(af[mi], wf[ni][ks], acc2[mi][ni], 0, 0, 0);
        }
#pragma unroll
        for (int mi = 0; mi < 4; ++mi)
#pragma unroll
            for (int reg = 0; reg < 4; ++reg) {
                int row = bm + wm + mi * 16 + lq * 4 + reg;
                if (row >= M) continue;
#pragma unroll
                for (int ni = 0; ni < 4; ++ni) {
                    int col = wn + ni * 16 + lr;
                    bf16 bv = __float2bfloat16(acc2[mi][ni][reg] + b2[col]);
                    C[(size_t)row * 128 + col] = *(ushort*)&bv;
                }
            }
    }
}

// ===== fused GRU v7: weight-stationary dbuf + LDS-coalesced store =====
// After MFMA, Ms[cur] is dead (next prefetch targets cur^1): epilogue writes
// outputs into Ms[cur] (swizzled hofs layout), then a wave-local coalesced
// copy-out (each wave reads the same linear slots it stages -> no cross-wave
// race with the next iteration's staging; disjoint row ranges per wave).
// Store insts per block: 8192x2B scattered -> 1024x16B coalesced.
__global__ __launch_bounds__(512, 2) void gru_fused(
    const ushort* __restrict__ mfeat, const ushort* __restrict__ wih,
    const ushort* __restrict__ whh, const float* __restrict__ bih,
    const float* __restrict__ bhh, ushort* __restrict__ node, int Nn, int nT)
{
    __shared__ ushort Ms[2][64 * 128];
    __shared__ ushort Hs[2][64 * 128];
    const int tid = threadIdx.x;
    const int lane = tid & 63, w = tid >> 6;
    const int lr = lane & 15, lq = lane >> 4;
    const int col = w * 16 + lr;
    short8 W[6][4];
#pragma unroll
    for (int ks = 0; ks < 4; ++ks) {
        int koff = ks * 32 + lq * 8;
        W[0][ks] = *(const short8*)(wih + (size_t)col * 128 + koff);
        W[1][ks] = *(const short8*)(wih + (size_t)(128 + col) * 128 + koff);
        W[2][ks] = *(const short8*)(wih + (size_t)(256 + col) * 128 + koff);
        W[3][ks] = *(const short8*)(whh + (size_t)col * 128 + koff);
        W[4][ks] = *(const short8*)(whh + (size_t)(128 + col) * 128 + koff);
        W[5][ks] = *(const short8*)(whh + (size_t)(256 + col) * 128 + koff);
    }
    const float br  = bih[col] + bhh[col];
    const float bz  = bih[128 + col] + bhh[128 + col];
    const float bin = bih[256 + col], bhn = bhh[256 + col];

    auto stage = [&](int tt, int buf) {
#pragma unroll
        for (int i = 0; i < 2; ++i) {
            int sb = w * 128 + i * 64;
            int s = sb + lane;
            int r = s >> 4;
            int c = (s & 15) ^ (r & 15);
            size_t goff = (size_t)(tt * 64 + r) * 128 + c * 8;
            gload_lds16(mfeat + goff, &Ms[buf][sb * 8]);
            gload_lds16(node + goff, &Hs[buf][sb * 8]);
        }
    };

    int t = blockIdx.x;
    const int G = gridDim.x;
    if (t >= nT) return;
    stage(t, 0);
    int cur = 0;
    while (t < nT) {
        int tn = t + G;
        if (tn < nT) {
            stage(tn, cur ^ 1);
            asm volatile("s_waitcnt vmcnt(4)" ::: "memory");
        } else {
            asm volatile("s_waitcnt vmcnt(0)" ::: "memory");
        }
        __builtin_amdgcn_sched_barrier(0);
        __builtin_amdgcn_s_barrier();   // tile-t staged data visible
        __builtin_amdgcn_sched_barrier(0);
        f32x4 aR[4] = {}, aZ[4] = {}, aN[4] = {}, aH[4] = {};
        {
            const ushort* Mc = Ms[cur];
            const ushort* Hc = Hs[cur];
#pragma unroll
            for (int ks = 0; ks < 4; ++ks) {
                int cb = ks * 4 + lq;
#pragma unroll
                for (int rt = 0; rt < 4; ++rt) {
                    int off = (rt * 16 + lr) * 128 + ((cb ^ lr) * 8);
                    short8 am = *(const short8*)(&Mc[off]);
                    short8 ah = *(const short8*)(&Hc[off]);
                    aR[rt] = __builtin_amdgcn_mfma_f32_16x16x32_bf16(am, W[0][ks], aR[rt], 0, 0, 0);
                    aR[rt] = __builtin_amdgcn_mfma_f32_16x16x32_bf16(ah, W[3][ks], aR[rt], 0, 0, 0);
                    aZ[rt] = __builtin_amdgcn_mfma_f32_16x16x32_bf16(am, W[1][ks], aZ[rt], 0, 0, 0);
                    aZ[rt] = __builtin_amdgcn_mfma_f32_16x16x32_bf16(ah, W[4][ks], aZ[rt], 0, 0, 0);
                    aN[rt] = __builtin_amdgcn_mfma_f32_16x16x32_bf16(am, W[2][ks], aN[rt], 0, 0, 0);
                    aH[rt] = __builtin_amdgcn_mfma_f32_16x16x32_bf16(ah, W[5][ks], aH[rt], 0, 0, 0);
                }
            }
        }
        __builtin_amdgcn_sched_barrier(0);
        __builtin_amdgcn_s_barrier();   // all MFMA reads of Ms[cur] done
        __builtin_amdgcn_sched_barrier(0);
        {
            ushort* Tc = Ms[cur];       // reuse as output staging
            const ushort* Hc = Hs[cur];
#pragma unroll
            for (int rt = 0; rt < 4; ++rt)
#pragma unroll
                for (int reg = 0; reg < 4; ++reg) {
                    int lrow = rt * 16 + lq * 4 + reg;
                    int hofs = lrow * 128 + (((col >> 3) ^ (lrow & 15)) * 8) + (col & 7);
                    float r = sigm(aR[rt][reg] + br);
                    float z = sigm(aZ[rt][reg] + bz);
                    float n = ftanh(aN[rt][reg] + bin + r * (aH[rt][reg] + bhn));
                    float hold = __bfloat162float(*(const bf16*)&Hc[hofs]);
                    bf16 hv = __float2bfloat16((1.f - z) * n + z * hold);
                    Tc[hofs] = *(ushort*)&hv;
                }
        }
        __builtin_amdgcn_sched_barrier(0);
        __builtin_amdgcn_s_barrier();   // epilogue writes visible
        __builtin_amdgcn_sched_barrier(0);
        {
            const int bm = t * 64;
#pragma unroll
            for (int i = 0; i < 2; ++i) {
                int s = w * 128 + i * 64 + lane;     // wave-local slots (same as stage)
                int r = s >> 4;
                int c = (s & 15) ^ (r & 15);
                int row = bm + r;
                if (row < Nn) {
                    uint4 v = *(const uint4*)(&Ms[cur][s * 8]);
                    *(uint4*)(node + (size_t)row * 128 + c * 8) = v;
                }
            }
        }
        cur ^= 1;
        t = tn;
    }
}

// ================= fused LSTM step (16 graphs/block) =================
__global__ __launch_bounds__(256) void lstm_fused(
    ushort* __restrict__ s, const ushort* __restrict__ Wl,
    const float* __restrict__ bih, const float* __restrict__ bhh,
    float* __restrict__ cl, int Gn)
{
    __shared__ ushort Ss[16 * 256];
    const int tid = threadIdx.x;
    const int bm = blockIdx.x * 16;
#pragma unroll
    for (int p = 0; p < 2; ++p) {
        int ch = p * 256 + tid;
        int r = ch >> 5, c = ch & 31;
        int row = bm + r;
        uint4 v = make_uint4(0u, 0u, 0u, 0u);
        if (row < Gn) v = *(const uint4*)(s + (size_t)row * 256 + c * 8);
        *(uint4*)(&Ss[r * 256 + ((c ^ (r & 15)) * 8)]) = v;
    }
    __syncthreads();
    const int lane = tid & 63, w = tid >> 6;
    const int lr = lane & 15, lq = lane >> 4;
    f32x4 acc[4][2] = {};
#pragma unroll
    for (int ks = 0; ks < 8; ++ks) {
        int cb = ks * 4 + lq;
        short8 am = *(const short8*)(&Ss[lr * 256 + ((cb ^ lr) * 8)]);
        int koff = ks * 32 + lq * 8;
#pragma unroll
        for (int g = 0; g < 4; ++g)
#pragma unroll
            for (int sub = 0; sub < 2; ++sub) {
                int col = g * 128 + w * 32 + sub * 16 + lr;
                short8 bf = *(const short8*)(Wl + (size_t)col * 256 + koff);
                acc[g][sub] = __builtin_amdgcn_mfma_f32_16x16x32_bf16(am, bf, acc[g][sub], 0, 0, 0);
            }
    }
#pragma unroll
    for (int sub = 0; sub < 2; ++sub) {
        int h = w * 32 + sub * 16 + lr;
        float bi = bih[h] + bhh[h];
        float bff = bih[128 + h] + bhh[128 + h];
        float bg = bih[256 + h] + bhh[256 + h];
        float bo = bih[384 + h] + bhh[384 + h];
#pragma unroll
        for (int reg = 0; reg < 4; ++reg) {
            int row = bm + lq * 4 + reg;
            if (row >= Gn) continue;
            float iv = sigm(acc[0][sub][reg] + bi);
            float fv = sigm(acc[1][sub][reg] + bff);
            float gv = ftanh(acc[2][sub][reg] + bg);
            float ov = sigm(acc[3][sub][reg] + bo);
            float c = fv * cl[(size_t)row * 128 + h] + iv * gv;
            cl[(size_t)row * 128 + h] = c;
            bf16 hv = __float2bfloat16(ov * ftanh(c));
            s[(size_t)row * 256 + h] = *(ushort*)&hv;
        }
    }
}

// ================= fused per-graph attention (vectorized, no reg cache) =========
__global__ __launch_bounds__(256) void att_fused(
    const ushort* __restrict__ node, ushort* __restrict__ s,
    const int* __restrict__ gptr)
{
    __shared__ float q[128];
    __shared__ float es[512];
    __shared__ float red[8];
    __shared__ float part[16][128];
    int g = blockIdx.x;
    int tid = threadIdx.x, lane = tid & 63, wid = tid >> 6;
    int n0 = gptr[g], n1 = gptr[g + 1];
    int cnt = n1 - n0; if (cnt > 512) cnt = 512;
    if (tid < 128) q[tid] = __bfloat162float(((const bf16*)s)[(size_t)g * 256 + tid]);
    __syncthreads();
    int gr = tid >> 4, c8 = (tid & 15) * 8;
    for (int i0 = 0; i0 < cnt; i0 += 16) {
        int i = i0 + gr;
        float p = 0.f;
        if (i < cnt) {
            uint4 v = *(const uint4*)(node + (size_t)(n0 + i) * TH + c8);
            float f[8]; unpack8(v, f);
#pragma unroll
            for (int j = 0; j < 8; ++j) p = fmaf(f[j], q[c8 + j], p);
        }
        p += __shfl_down(p, 8, 16);
        p += __shfl_down(p, 4, 16);
        p += __shfl_down(p, 2, 16);
        p += __shfl_down(p, 1, 16);
        if ((tid & 15) == 0 && i < cnt) es[i] = p;
    }
    __syncthreads();
    float m = -1e30f;
    for (int i = tid; i < cnt; i += 256) m = fmaxf(m, es[i]);
    for (int off = 32; off; off >>= 1) m = fmaxf(m, __shfl_down(m, off));
    if (lane == 0) red[wid] = m;
    __syncthreads();
    m = fmaxf(fmaxf(red[0], red[1]), fmaxf(red[2], red[3]));
    float sm = 0.f;
    for (int i = tid; i < cnt; i += 256) { float ex = __expf(es[i] - m); es[i] = ex; sm += ex; }
    for (int off = 32; off; off >>= 1) sm += __shfl_down(sm, off);
    if (lane == 0) red[4 + wid] = sm;
    __syncthreads();
    sm = red[4] + red[5] + red[6] + red[7];
    float inv = 1.f / fmaxf(sm, 1e-9f);
    float racc[8] = {};
    for (int i = gr; i < cnt; i += 16) {
        uint4 v = *(const uint4*)(node + (size_t)(n0 + i) * TH + c8);
        float f[8]; unpack8(v, f);
        float a = es[i];
#pragma unroll
        for (int j = 0; j < 8; ++j) racc[j] = fmaf(a, f[j], racc[j]);
    }
#pragma unroll
    for (int j = 0; j < 8; ++j) part[gr][c8 + j] = racc[j];
    __syncthreads();
    if (tid < 128) {
        float r = 0.f;
#pragma unroll
        for (int k = 0; k < 16; ++k) r += part[k][tid];
        bf16 rv = __float2bfloat16(r * inv);
        s[(size_t)g * 256 + 128 + tid] = *(ushort*)&rv;
    }
}

// ===== final FC, 16 graphs/block: w1 loaded once per 16 graphs (16x less L2) =====
__global__ __launch_bounds__(256) void final_fc16(
    const ushort* __restrict__ s,
    const float* __restrict__ w1, const float* __restrict__ b1,
    const float* __restrict__ w2, const float* __restrict__ b2,
    float* __restrict__ out, int Gn)
{
    __shared__ float qsL[16][264];
    __shared__ float hsum[2][16][136];
    const int tid = threadIdx.x;
    const int g0 = blockIdx.x * 16;
    // stage 16 graphs x 256 ch (bf16 -> f32), coalesced
#pragma unroll
    for (int p = 0; p < 2; ++p) {
        int slot = p * 256 + tid;          // 0..511
        int g = slot >> 5, c = slot & 31;
        int row = g0 + g;
        uint4 v = make_uint4(0u, 0u, 0u, 0u);
        if (row < Gn) v = *(const uint4*)(s + (size_t)row * 256 + c * 8);
        float f[8]; unpack8(v, f);
#pragma unroll
        for (int j = 0; j < 8; ++j) qsL[g][c * 8 + j] = f[j];
    }
    __syncthreads();
    const int h = tid & 127, half = tid >> 7;
    float acc[16];
#pragma unroll
    for (int g = 0; g < 16; ++g) acc[g] = 0.f;
    const int k0 = half * 128;
    for (int k = 0; k < 128; ++k) {
        float wv = w1[(size_t)(k0 + k) * 128 + h];
#pragma unroll
        for (int g = 0; g < 16; ++g) acc[g] = fmaf(qsL[g][k0 + k], wv, acc[g]);
    }
#pragma unroll
    for (int g = 0; g < 16; ++g) hsum[half][g][h] = acc[g];
    __syncthreads();
    const int gi = tid >> 4, l16 = tid & 15;
    float p = 0.f;
    for (int hh = l16; hh < 128; hh += 16) {
        float v = hsum[0][gi][hh] + hsum[1][gi][hh] + b1[hh];
        p = fmaf(fmaxf(v, 0.f), w2[hh], p);
    }
#pragma unroll
    for (int off = 8; off; off >>= 1) p += __shfl_xor(p, off, 16);
    if (l16 == 0 && g0 + gi < Gn) out[g0 + gi] = p + b2[0];
}

// ---------------------------------------------------------------------------
static void launch_mlp2(const void* A, const bf16* W1t, const float* b1,
                        const bf16* W2t, const float* b2, void* C, int M, hipStream_t s) {
    hipLaunchKernelGGL(mlp2_fused, dim3((M + 127) / 128), dim3(256), 0, s,
                       (const ushort*)A, (const ushort*)W1t, b1, (const ushort*)W2t, b2,
                       (ushort*)C, M);
}

extern "C" void kernel_launch(void* const* d_in, const int* in_sizes, int n_in,
                              void* d_out, int out_size, void* d_ws, size_t ws_size,
                              hipStream_t stream) {
    const float* x         = (const float*)d_in[0];
    const float* edge_attr = (const float*)d_in[1];
    const int*   edge_index= (const int*)d_in[2];
    const int*   batch     = (const int*)d_in[3];
    const float* node_w    = (const float*)d_in[4];
    const float* node_b    = (const float*)d_in[5];
    const float* edge_w    = (const float*)d_in[6];
    const float* edge_b    = (const float*)d_in[7];
    const float* eps       = (const float*)d_in[8];
    const float* gin_w1    = (const float*)d_in[9];
    const float* gin_b1    = (const float*)d_in[10];
    const float* gin_w2    = (const float*)d_in[11];
    const float* gin_b2    = (const float*)d_in[12];
    const float* em_w1     = (const float*)d_in[13];
    const float* em_b1     = (const float*)d_in[14];
    const float* em_w2     = (const float*)d_in[15];
    const float* em_b2     = (const float*)d_in[16];
    const float* gru_wih   = (const float*)d_in[17];
    const float* gru_whh   = (const float*)d_in[18];
    const float* gru_bih   = (const float*)d_in[19];
    const float* gru_bhh   = (const float*)d_in[20];
    const float* lstm_wih  = (const float*)d_in[21];
    const float* lstm_whh  = (const float*)d_in[22];
    const float* lstm_bih  = (const float*)d_in[23];
    const float* lstm_bhh  = (const float*)d_in[24];
    const float* fc_w1     = (const float*)d_in[25];
    const float* fc_b1     = (const float*)d_in[26];
    const float* fc_w2     = (const float*)d_in[27];
    const float* fc_b2     = (const float*)d_in[28];
    float* out = (float*)d_out;
    const int* ei_src = edge_index;
    const int* ei_dst = edge_index + TE;

    // ---- workspace layout ----
    char* base = (char*)d_ws;
    size_t off = 0;
    auto alloc = [&](size_t bytes) { void* p = base + off; off += (bytes + 15) & ~size_t(15); return p; };
    bf16*  nodeb = (bf16*)alloc((size_t)TN * TH * 2);   // 25.6 MB
    bf16*  zb    = (bf16*)alloc((size_t)TN * TH * 2);   // 25.6 MB
    bf16*  e1b   = (bf16*)alloc((size_t)TE * TH * 2);   // 51.2 MB (set2set overlay later)
    int*   deg   = (int*)alloc((size_t)TN * 4);
    int*   rowptr= (int*)alloc((size_t)(TN + 1) * 4);
    int*   cur   = (int*)alloc((size_t)TN * 4);
    int*   srcp  = (int*)alloc((size_t)TE * 4);
    int*   epos  = (int*)alloc((size_t)TE * 4);
    int*   bsum  = (int*)alloc(512 * 4);
    int*   bsumx = (int*)alloc(512 * 4);
    int*   gptr  = (int*)alloc((size_t)(TG + 1) * 4);
    bf16*  w6    = (bf16*)alloc(6 * TH * TH * 2);
    bf16*  wgru  = (bf16*)alloc(2 * 384 * TH * 2);
    bf16*  wl    = (bf16*)alloc(512 * 256 * 2);
    if (ws_size < off) return;

    bf16* w_gin1_0 = w6;
    bf16* w_gin1_1 = w6 + 1 * TH * TH;
    bf16* w_gin2_0 = w6 + 2 * TH * TH;
    bf16* w_gin2_1 = w6 + 3 * TH * TH;
    bf16* w_em1    = w6 + 4 * TH * TH;
    bf16* w_em2    = w6 + 5 * TH * TH;
    bf16* w_wih    = wgru;
    bf16* w_whh    = wgru + 384 * TH;

    ushort* sbuf = (ushort*)e1b;                      // [G][256] bf16
    float*  cl   = (float*)(sbuf + (size_t)TG * 256); // [G][128] fp32

    // ---- CSR + gptr ----
    hipMemsetAsync(deg, 0, (size_t)TN * 4, stream);
    hipMemsetAsync(cur, 0, (size_t)TN * 4, stream);
    count_deg<<<(TE + 255) / 256, 256, 0, stream>>>(ei_dst, deg, TE);
    int nb = (TN + 255) / 256;
    scan_block<<<nb, 256, 0, stream>>>(deg, rowptr, bsum, TN);
    scan_bsum<<<1, 512, 0, stream>>>(bsum, bsumx, nb);
    add_off<<<nb, 256, 0, stream>>>(rowptr, bsumx, TN, TE);
    fill_csr<<<(TE + 255) / 256, 256, 0, stream>>>(ei_src, ei_dst, rowptr, cur, srcp, epos, TE);
    build_gptr<<<(TN + 255) / 256, 256, 0, stream>>>(batch, gptr, TN, TG);

    // ---- weights (one merged kernel) ----
    int convTot = 6 * TH * TH + 2 * 384 * TH + 512 * 256;
    convAll<<<(convTot + 255) / 256, 256, 0, stream>>>(
        gin_w1, gin_w2, em_w1, em_w2, gru_wih, gru_whh, lstm_wih, lstm_whh,
        w6, wgru, wl);

    // ---- projections (edges scattered into CSR slot order) ----
    proj64<14><<<(TN + 63) / 64, 256, 0, stream>>>(x, node_w, node_b, (ushort*)nodeb, TN);
    proj_scatter<<<(TE + 63) / 64, 256, 0, stream>>>(edge_attr, edge_w, edge_b,
                                                     epos, (ushort*)e1b, TE);

    const int ntG = (TN + 63) / 64;   // gru tiles

    // ---- layer 0: aggregate -> zb; MLP in-place; GRU ----
    aggregate_v8<<<(TN * 16 + 255) / 256, 256, 0, stream>>>(
        (const ushort*)nodeb, (const ushort*)e1b, srcp, rowptr, eps, 0, (ushort*)zb, TN);
    launch_mlp2(zb, w_gin1_0, gin_b1, w_gin2_0, gin_b2, zb, TN, stream);
    gru_fused<<<512, 512, 0, stream>>>(
        (const ushort*)zb, (const ushort*)w_wih, (const ushort*)w_whh,
        gru_bih, gru_bhh, (ushort*)nodeb, TN, ntG);

    // ---- edge MLP in-place (slot order preserved), layer 1 ----
    launch_mlp2(e1b, w_em1, em_b1, w_em2, em_b2, e1b, TE, stream);
    aggregate_v8<<<(TN * 16 + 255) / 256, 256, 0, stream>>>(
        (const ushort*)nodeb, (const ushort*)e1b, srcp, rowptr, eps, 1, (ushort*)zb, TN);
    launch_mlp2(zb, w_gin1_1, gin_b1 + TH, w_gin2_1, gin_b2 + TH, zb, TN, stream);
    gru_fused<<<512, 512, 0, stream>>>(
        (const ushort*)zb, (const ushort*)w_wih, (const ushort*)w_whh,
        gru_bih, gru_bhh, (ushort*)nodeb, TN, ntG);

    // ---- Set2Set (3 steps) ----
    hipMemsetAsync(sbuf, 0, (size_t)TG * 256 * 2 + (size_t)TG * 128 * 4, stream);
    for (int st = 0; st < 3; ++st) {
        lstm_fused<<<(TG + 15) / 16, 256, 0, stream>>>(
            sbuf, (const ushort*)wl, lstm_bih, lstm_bhh, cl, TG);
        att_fused<<<TG, 256, 0, stream>>>((const ushort*)nodeb, sbuf, gptr);
    }

    // ---- final FC (16 graphs/block) ----
    final_fc16<<<(TG + 15) / 16, 256, 0, stream>>>(
        sbuf, fc_w1, fc_b1, fc_w2, fc_b2, out, TG);
}